// Round 2
// baseline (566.492 us; speedup 1.0000x reference)
//
#include <hip/hip_runtime.h>
#include <math.h>

#define NN 50000
#define MM 800000
#define HH 64
#define NB_EDGE 1024
#define NTILE 12500                 // MM / 64 edges per block-tile

typedef short bf16x8 __attribute__((ext_vector_type(8)));
typedef float f32x4  __attribute__((ext_vector_type(4)));

// per-wave LDS fence: all LDS regions are wave-private; lockstep + lgkmcnt
// drain replaces __syncthreads
#define WFENCE() asm volatile("s_waitcnt lgkmcnt(0)" ::: "memory")

__device__ __forceinline__ float silu_f(float v) {
    return v * __builtin_amdgcn_rcpf(1.0f + __expf(-v));
}
// round-half-up fp32 -> bf16 bits (0.5 ulp max)
__device__ __forceinline__ unsigned short bfb(float a) {
    return (unsigned short)((__float_as_uint(a) + 0x8000u) >> 16);
}
// pack two f32 -> bf16x2 via v_perm (low = a, high = b)
__device__ __forceinline__ unsigned pk2(float a, float b) {
    return __builtin_amdgcn_perm(__float_as_uint(b) + 0x8000u,
                                 __float_as_uint(a) + 0x8000u, 0x07060302u);
}
__device__ __forceinline__ float b2f(unsigned short s) {
    return __uint_as_float((unsigned)s << 16);
}
// packed bf16x2 atomic add
__device__ __forceinline__ void atomic_pk_bf16(unsigned short* addr, unsigned pk) {
    asm volatile("global_atomic_pk_add_bf16 %0, %1, off"
                 :: "v"((unsigned long long)(size_t)addr), "v"(pk) : "memory");
}

// ---------------- fused setup ----------------
// blocks [0,3125): deg histogram
// blocks [3125,3365): weight pre-swizzle (per layer 30720 shorts)
// blocks [3365,15865): embedding
// blocks [15865,17574): zero sum_f+tmsgb (7,000,000 B)
// blocks [17574,17721): copy x_in -> xo (uint4)
// blocks [17721,17917): build padded x4 mirror
__global__ __launch_bounds__(256) void setup_kernel(
    const int* __restrict__ row, int* __restrict__ deg,
    const float* __restrict__ eW1, const float* __restrict__ eW2,
    const float* __restrict__ cW1, const float* __restrict__ nW1,
    const float* __restrict__ nW2, unsigned short* __restrict__ wsW,
    const float* __restrict__ h_in, const float* __restrict__ emb_W,
    const float* __restrict__ emb_b, float* __restrict__ h_out,
    unsigned short* __restrict__ hb,
    char* __restrict__ zbase, const float* __restrict__ x_in,
    float* __restrict__ xo, float* __restrict__ x4)
{
    const int b = blockIdx.x;
    if (b < 3125) {
        const int e = b * 256 + threadIdx.x;
        atomicAdd(&deg[row[e]], 1);
    } else if (b < 3365) {
        const int i = (b - 3125) * 256 + threadIdx.x;     // 0 .. 61439
        const int layer = i / 30720;
        const int rem = i - layer * 30720;
        float val;
        if (rem < 10240) {
            const int j = rem & 7, lane = (rem >> 3) & 63, nt = (rem >> 9) & 3, s = rem >> 11;
            const int kp = s * 32 + ((lane >> 4) << 3) + j;
            const int n  = nt * 16 + (lane & 15);
            if (kp > 136) val = 0.0f;
            else {
                const int k = (kp == 136) ? 0 : kp + 1;   // k'=136 is the r2 row
                val = eW1[layer * 137 * 64 + k * 64 + n];
            }
        } else if (rem < 14336) {
            const int r2 = rem - 10240;
            const int j = r2 & 7, lane = (r2 >> 3) & 63, nt = (r2 >> 9) & 3, s = r2 >> 11;
            val = eW2[layer * 4096 + (s * 32 + ((lane >> 4) << 3) + j) * 64 + nt * 16 + (lane & 15)];
        } else if (rem < 18432) {
            const int r3 = rem - 14336;
            const int j = r3 & 7, lane = (r3 >> 3) & 63, nt = (r3 >> 9) & 3, s = r3 >> 11;
            val = cW1[layer * 4096 + (s * 32 + ((lane >> 4) << 3) + j) * 64 + nt * 16 + (lane & 15)];
        } else if (rem < 26624) {
            const int r4 = rem - 18432;
            const int j = r4 & 7, lane = (r4 >> 3) & 63, nt = (r4 >> 9) & 3, s = r4 >> 11;
            const int kp = s * 32 + ((lane >> 4) << 3) + j;      // < 128
            val = nW1[layer * 8192 + kp * 64 + nt * 16 + (lane & 15)];
        } else {
            const int r5 = rem - 26624;
            const int j = r5 & 7, lane = (r5 >> 3) & 63, nt = (r5 >> 9) & 3, s = r5 >> 11;
            val = nW2[layer * 4096 + (s * 32 + ((lane >> 4) << 3) + j) * 64 + nt * 16 + (lane & 15)];
        }
        wsW[i] = bfb(val);
    } else if (b < 15865) {
        const int idx = (b - 3365) * 256 + threadIdx.x;   // over N*64
        const int n = idx >> 6, j = idx & 63;
        float acc = emb_b[j];
        #pragma unroll
        for (int k = 0; k < 16; ++k)
            acc += h_in[n * 16 + k] * emb_W[k * HH + j];
        h_out[idx] = acc;
        hb[idx] = bfb(acc);
    } else if (b < 17574) {
        const int t = (b - 15865) * 256 + threadIdx.x;
        if (t < 437500) {                                  // 7,000,000 / 16
            const uint4 z = {0u, 0u, 0u, 0u};
            *(uint4*)(zbase + (size_t)t * 16) = z;
        }
    } else if (b < 17721) {
        const int t = (b - 17574) * 256 + threadIdx.x;
        if (t < 37500)                                     // N*3 floats / 4
            ((uint4*)xo)[t] = ((const uint4*)x_in)[t];
    } else {
        const int n = (b - 17721) * 256 + threadIdx.x;
        if (n < NN) {
            float4 v;
            v.x = x_in[3 * n + 0];
            v.y = x_in[3 * n + 1];
            v.z = x_in[3 * n + 2];
            v.w = 0.0f;
            ((float4*)x4)[n] = v;
        }
    }
}

// parallel scan over NN, phase A: 200 blocks x 250-node chunks -> blocksum
__global__ __launch_bounds__(256) void scanA_kernel(const int* __restrict__ deg,
                                                    int* __restrict__ bsum) {
    __shared__ int ps[256];
    const int t = threadIdx.x;
    const int base = blockIdx.x * 250;
    int v = (t < 250) ? deg[base + t] : 0;
    ps[t] = v;
    __syncthreads();
    for (int off = 1; off < 256; off <<= 1) {
        const int u = (t >= off) ? ps[t - off] : 0;
        __syncthreads();
        ps[t] += u;
        __syncthreads();
    }
    if (t == 255) bsum[blockIdx.x] = ps[255];
}

// phase B: exclusive scan of 200 blocksums (single small block)
__global__ __launch_bounds__(256) void scanB_kernel(const int* __restrict__ bsum,
                                                    int* __restrict__ boff) {
    __shared__ int ps[256];
    const int t = threadIdx.x;
    int v = (t < 200) ? bsum[t] : 0;
    ps[t] = v;
    __syncthreads();
    for (int off = 1; off < 256; off <<= 1) {
        const int u = (t >= off) ? ps[t - off] : 0;
        __syncthreads();
        ps[t] += u;
        __syncthreads();
    }
    if (t < 200) boff[t] = ps[t] - v;     // exclusive
}

// phase C: per-chunk exclusive scan + global offset -> cur
__global__ __launch_bounds__(256) void scanC_kernel(const int* __restrict__ deg,
                                                    const int* __restrict__ boff,
                                                    int* __restrict__ cur) {
    __shared__ int ps[256];
    const int t = threadIdx.x;
    const int base = blockIdx.x * 250;
    int v = (t < 250) ? deg[base + t] : 0;
    ps[t] = v;
    __syncthreads();
    for (int off = 1; off < 256; off <<= 1) {
        const int u = (t >= off) ? ps[t - off] : 0;
        __syncthreads();
        ps[t] += u;
        __syncthreads();
    }
    if (t < 250)
        cur[base + t] = boff[blockIdx.x] + ps[t] - v;   // exclusive prefix
}

// one-pass counting-sort fill: rc (int2 interleaved) + efs in row-sorted order
__global__ __launch_bounds__(256) void fill_kernel(
    const int* __restrict__ row, const int* __restrict__ col,
    const float* __restrict__ efea, int* __restrict__ cur,
    int2* __restrict__ rc, unsigned short* __restrict__ efs)
{
    const int e = blockIdx.x * 256 + threadIdx.x;
    const int r = row[e];
    const int pos = atomicAdd(&cur[r], 1);
    int2 v; v.x = r; v.y = col[e];
    rc[pos] = v;                                       // one 8B scatter
    const float4* ef = (const float4*)(efea + (size_t)e * 8);
    const float4 e0 = ef[0], e1 = ef[1];
    uint4 ue = { pk2(e0.x, e0.y), pk2(e0.z, e0.w), pk2(e1.x, e1.y), pk2(e1.z, e1.w) };
    *(uint4*)(efs + (size_t)pos * 8) = ue;
}

// ---------------- MFMA edge kernel: 16 sorted edges per wave ----------------
// Segmented flush with packed-bf16 atomics; rows sorted -> ~2 segments/tile.
// Weights: GEMM1 fragments hoisted to registers/AGPRs; GEMM2+GEMM3 weights in
// block-shared LDS. Gather is software-pipelined one tile deep (T14): tile
// t+1's global loads are issued before tile t's GEMMs, so ~L2/L3 latency
// hides under the compute phase instead of stalling the LDS-write.
__global__ __launch_bounds__(256, 4) void edge_mfma_kernel(
    const float* __restrict__ x4, const unsigned short* __restrict__ hb,
    const int2* __restrict__ rc, const unsigned short* __restrict__ efs,
    const unsigned short* __restrict__ w1b, const unsigned short* __restrict__ w2b,
    const unsigned short* __restrict__ cw1b,
    const float* __restrict__ b1, const float* __restrict__ b2,
    const float* __restrict__ cb1, const float* __restrict__ cw2,
    const float* __restrict__ cb2,
    float* __restrict__ sum_f, unsigned short* __restrict__ tmsgb)
{
    __shared__ __align__(16) unsigned short S[4][16][168];
    __shared__ float RV[4][16][4];
    __shared__ int   RI[4][16];
    __shared__ __align__(16) unsigned short WS[8192];  // [0,4096)=w2b  [4096,8192)=cw1b

    const int tid = threadIdx.x;
    const int w = tid >> 6, lane = tid & 63;
    const int l15 = lane & 15, quad = lane >> 4;
    const int le = lane >> 2, sub = lane & 3;

    // stage GEMM2/GEMM3 weights into LDS, block-shared (512 uint4 each)
    {
        const uint4* s2 = (const uint4*)w2b;
        const uint4* s3 = (const uint4*)cw1b;
        uint4* dst = (uint4*)WS;
        dst[tid]       = s2[tid];
        dst[256 + tid] = s2[256 + tid];
        dst[512 + tid] = s3[tid];
        dst[768 + tid] = s3[256 + tid];
    }

    // hoist GEMM1 weight fragments into registers (loop-invariant; AGPR-parked)
    bf16x8 w1f[5][4];
    #pragma unroll
    for (int s = 0; s < 5; ++s)
        #pragma unroll
        for (int nt = 0; nt < 4; ++nt)
            w1f[s][nt] = *(const bf16x8*)(w1b + ((s * 4 + nt) * 64 + lane) * 8);

    float b1v[4], b2v[4], cb1v[4], cw2v[4];
    #pragma unroll
    for (int nt = 0; nt < 4; ++nt) {
        b1v[nt]  = b1[nt * 16 + l15];
        b2v[nt]  = b2[nt * 16 + l15];
        cb1v[nt] = cb1[nt * 16 + l15];
        cw2v[nt] = cw2[nt * 16 + l15];
    }
    const float cb2s = cb2[0];

    {   // zero the K-pad [138,160) once; never overwritten afterwards
        unsigned short* Sr = &S[w][le][0];
        if (sub == 0) {
            *(unsigned*)&Sr[138] = 0u; *(unsigned*)&Sr[140] = 0u; *(unsigned*)&Sr[142] = 0u;
        } else if (sub == 1) {
            *(unsigned*)&Sr[144] = 0u; *(unsigned*)&Sr[146] = 0u;
            *(unsigned*)&Sr[148] = 0u; *(unsigned*)&Sr[150] = 0u;
        } else if (sub == 2) {
            *(unsigned*)&Sr[152] = 0u; *(unsigned*)&Sr[154] = 0u;
            *(unsigned*)&Sr[156] = 0u; *(unsigned*)&Sr[158] = 0u;
        }
    }
    __syncthreads();   // WS visible to all 4 waves; also drains K-pad writes

    // ---- pipeline prologue: payload for first tile ----
    const int lofs = w * 16 + le;
    int btc = blockIdx.x;
    int btn = btc + NB_EDGE;
    int2 rcv = rc[btc * 64 + lofs];
    uint4 u0, u1, v0, v1, ef;
    float4 xr, xc;
    {
        const unsigned short* hr = hb + (size_t)rcv.x * HH + sub * 16;
        u0 = *(const uint4*)(hr);
        u1 = *(const uint4*)(hr + 8);
        const unsigned short* hc = hb + (size_t)rcv.y * HH + sub * 16;
        v0 = *(const uint4*)(hc);
        v1 = *(const uint4*)(hc + 8);
        if (sub == 0) {
            xr = ((const float4*)x4)[rcv.x];
            xc = ((const float4*)x4)[rcv.y];
        } else if (sub == 1) {
            ef = *(const uint4*)(efs + ((size_t)btc * 64 + lofs) * 8);
        }
    }
    int2 rcn = rc[(btn < NTILE ? btn : btc) * 64 + lofs];

    for (; btc < NTILE; btc = btn, btn += NB_EDGE) {
        const bool have_next = (btn < NTILE);

        // ---- step 1: payload regs -> LDS ----
        unsigned short* Srow = &S[w][le][0];
        *(uint4*)&Srow[sub * 16]          = u0;
        *(uint4*)&Srow[sub * 16 + 8]      = u1;
        *(uint4*)&Srow[64 + sub * 16]     = v0;
        *(uint4*)&Srow[64 + sub * 16 + 8] = v1;
        if (sub == 0) {
            const float rx = xr.x - xc.x;
            const float ry = xr.y - xc.y;
            const float rz = xr.z - xc.z;
            const float r2 = rx * rx + ry * ry + rz * rz;
            RV[w][le][0] = rx; RV[w][le][1] = ry; RV[w][le][2] = rz;
            RI[w][le] = rcv.x;
            *(unsigned*)&Srow[136] = (unsigned)bfb(r2);   // zeroes col 137 too
        } else if (sub == 1) {
            *(uint4*)&Srow[128] = ef;
        }

        // ---- step 2: issue next tile's payload (flies across the GEMMs) ----
        if (have_next) {
            const unsigned short* hr = hb + (size_t)rcn.x * HH + sub * 16;
            u0 = *(const uint4*)(hr);
            u1 = *(const uint4*)(hr + 8);
            const unsigned short* hc = hb + (size_t)rcn.y * HH + sub * 16;
            v0 = *(const uint4*)(hc);
            v1 = *(const uint4*)(hc + 8);
            if (sub == 0) {
                xr = ((const float4*)x4)[rcn.x];
                xc = ((const float4*)x4)[rcn.y];
            } else if (sub == 1) {
                ef = *(const uint4*)(efs + ((size_t)btn * 64 + lofs) * 8);
            }
            rcv = rcn;
            const int bt2 = btn + NB_EDGE;
            rcn = rc[(bt2 < NTILE ? bt2 : btn) * 64 + lofs];
        }
        WFENCE();

        // ---- GEMM1: S[16x160] @ W1[160x64] -> H1 (alias cols 0..63) ----
        bf16x8 af[5];
        #pragma unroll
        for (int s = 0; s < 5; ++s)
            af[s] = *(const bf16x8*)&S[w][l15][s * 32 + quad * 8];
        WFENCE();   // af in regs before H1 overwrites the same cols
        #pragma unroll
        for (int nt = 0; nt < 4; ++nt) {
            f32x4 a = {0.f, 0.f, 0.f, 0.f};
            #pragma unroll
            for (int s = 0; s < 5; ++s)
                a = __builtin_amdgcn_mfma_f32_16x16x32_bf16(af[s], w1f[s][nt], a, 0, 0, 0);
            #pragma unroll
            for (int rr = 0; rr < 4; ++rr)
                S[w][quad * 4 + rr][nt * 16 + l15] = bfb(silu_f(a[rr] + b1v[nt]));
        }
        WFENCE();

        // ---- GEMM2: H1 @ W2 -> msg (alias back into cols 0..63) ----
        bf16x8 a2[2];
        #pragma unroll
        for (int s = 0; s < 2; ++s)
            a2[s] = *(const bf16x8*)&S[w][l15][s * 32 + quad * 8];
        WFENCE();   // a2 in regs before MS overwrites
        #pragma unroll
        for (int nt = 0; nt < 4; ++nt) {
            f32x4 m = {0.f, 0.f, 0.f, 0.f};
            #pragma unroll
            for (int s = 0; s < 2; ++s) {
                bf16x8 bf = *(const bf16x8*)&WS[((s * 4 + nt) * 64 + lane) * 8];
                m = __builtin_amdgcn_mfma_f32_16x16x32_bf16(a2[s], bf, m, 0, 0, 0);
            }
            #pragma unroll
            for (int rr = 0; rr < 4; ++rr)
                S[w][quad * 4 + rr][nt * 16 + l15] = bfb(silu_f(m[rr] + b2v[nt]));
        }
        WFENCE();

        // ---- GEMM3: msg @ cW1 -> c1; dot cW2 -> cm (cols 160..162) ----
        bf16x8 a3[2];
        #pragma unroll
        for (int s = 0; s < 2; ++s)
            a3[s] = *(const bf16x8*)&S[w][l15][s * 32 + quad * 8];
        float pr[4] = {0.f, 0.f, 0.f, 0.f};
        #pragma unroll
        for (int nt = 0; nt < 4; ++nt) {
            f32x4 q = {0.f, 0.f, 0.f, 0.f};
            #pragma unroll
            for (int s = 0; s < 2; ++s) {
                bf16x8 bf = *(const bf16x8*)&WS[4096 + ((s * 4 + nt) * 64 + lane) * 8];
                q = __builtin_amdgcn_mfma_f32_16x16x32_bf16(a3[s], bf, q, 0, 0, 0);
            }
            #pragma unroll
            for (int rr = 0; rr < 4; ++rr)
                pr[rr] += silu_f(q[rr] + cb1v[nt]) * cw2v[nt];
        }
        #pragma unroll
        for (int rr = 0; rr < 4; ++rr) {
            float tt = pr[rr];
            tt += __shfl_xor(tt, 1, 64);
            tt += __shfl_xor(tt, 2, 64);
            tt += __shfl_xor(tt, 4, 64);
            tt += __shfl_xor(tt, 8, 64);
            if (l15 == 0) *(float*)&S[w][quad * 4 + rr][160] = tt + cb2s;
        }
        WFENCE();

        // ---- segmented flush: rows sorted by RI within the tile ----
        if (lane < 32) {   // msg -> tmsgb: lane owns cols {2l, 2l+1}, pk atomic
            unsigned both = *(const unsigned*)&S[w][0][2 * lane];
            float ax = b2f((unsigned short)(both & 0xffffu));
            float ay = b2f((unsigned short)(both >> 16));
            int cur_r = RI[w][0];
            #pragma unroll
            for (int g = 1; g < 16; ++g) {
                const int ri = RI[w][g];
                unsigned bv = *(const unsigned*)&S[w][g][2 * lane];
                const float vx = b2f((unsigned short)(bv & 0xffffu));
                const float vy = b2f((unsigned short)(bv >> 16));
                if (ri != cur_r) {
                    atomic_pk_bf16(&tmsgb[(size_t)cur_r * HH + 2 * lane], pk2(ax, ay));
                    ax = 0.f; ay = 0.f; cur_r = ri;
                }
                ax += vx; ay += vy;
            }
            atomic_pk_bf16(&tmsgb[(size_t)cur_r * HH + 2 * lane], pk2(ax, ay));
        } else if ((lane & 31) < 3) {   // f = rij*cm -> sum_f (fp32, tiny)
            const int sl = lane & 31;
            float acc = RV[w][0][sl] * (*(const float*)&S[w][0][160]);
            int cur_r = RI[w][0];
            #pragma unroll
            for (int g = 1; g < 16; ++g) {
                const int ri = RI[w][g];
                const float v = RV[w][g][sl] * (*(const float*)&S[w][g][160]);
                if (ri != cur_r) {
                    atomicAdd(&sum_f[3 * cur_r + sl], acc);
                    acc = 0.f; cur_r = ri;
                }
                acc += v;
            }
            atomicAdd(&sum_f[3 * cur_r + sl], acc);
        }
        WFENCE();
    }
}

// ---------------- MFMA node kernel: 16 nodes per wave ----------------
// Reads bf16 tmsgb directly; zeroes tmsgb/sum_f after use (next layer's init).
// Updates both xo (output) and x4 (padded mirror for next layer's edge pass).
__global__ __launch_bounds__(256) void node_mfma_kernel(
    float* __restrict__ x, float* __restrict__ x4, float* __restrict__ h,
    unsigned short* __restrict__ hb,
    float* __restrict__ sum_f, const int* __restrict__ deg,
    unsigned short* __restrict__ tmsgb,
    const unsigned short* __restrict__ nw1b, const unsigned short* __restrict__ nw2b,
    const float* __restrict__ nb1, const float* __restrict__ nb2)
{
    __shared__ __align__(16) unsigned short S[4][16][136];
    const int tid = threadIdx.x;
    const int w = tid >> 6, lane = tid & 63;
    const int l15 = lane & 15, quad = lane >> 4;
    const int le = lane >> 2, sub = lane & 3;
    const int t = blockIdx.x * 4 + w;
    if (t >= NN / 16) return;                      // 3125 waves exactly

    // gather (fully coalesced): [hb | tmsgb] -> S[16][128]; zero tmsgb after
    {
        unsigned short* Srow = &S[w][le][0];
        const int n = t * 16 + le;
        const unsigned short* hr = hb + (size_t)n * HH + sub * 16;
        *(uint4*)&Srow[sub * 16]     = *(const uint4*)(hr);
        *(uint4*)&Srow[sub * 16 + 8] = *(const uint4*)(hr + 8);
        unsigned short* tm = tmsgb + (size_t)n * HH + sub * 16;
        *(uint4*)&Srow[64 + sub * 16]     = *(const uint4*)(tm);
        *(uint4*)&Srow[64 + sub * 16 + 8] = *(const uint4*)(tm + 8);
        const uint4 z = {0u, 0u, 0u, 0u};
        *(uint4*)(tm)     = z;
        *(uint4*)(tm + 8) = z;
    }
    // x update: one lane per node; zero sum_f after
    if (lane < 16) {
        const int nn = t * 16 + lane;
        const float cn = fmaxf((float)deg[nn], 1.0f);
        const float rc = __builtin_amdgcn_rcpf(cn);
        #pragma unroll
        for (int d3 = 0; d3 < 3; ++d3) {
            float tf = sum_f[3 * nn + d3] * rc;
            tf = fminf(fmaxf(tf, -100.0f), 100.0f);
            x[3 * nn + d3] += tf;
            x4[4 * nn + d3] += tf;
            sum_f[3 * nn + d3] = 0.0f;
        }
    }
    WFENCE();

    // GEMM1: [16x128] @ nW1[128x64] -> SiLU -> alias cols 0..63
    bf16x8 af[4];
    #pragma unroll
    for (int s = 0; s < 4; ++s)
        af[s] = *(const bf16x8*)&S[w][l15][s * 32 + quad * 8];
    WFENCE();
    float nb1v[4], nb2v[4];
    #pragma unroll
    for (int nt = 0; nt < 4; ++nt) {
        nb1v[nt] = nb1[nt * 16 + l15];
        nb2v[nt] = nb2[nt * 16 + l15];
    }
    #pragma unroll
    for (int nt = 0; nt < 4; ++nt) {
        f32x4 a = {0.f, 0.f, 0.f, 0.f};
        #pragma unroll
        for (int s = 0; s < 4; ++s) {
            bf16x8 bf = *(const bf16x8*)(nw1b + ((s * 4 + nt) * 64 + lane) * 8);
            a = __builtin_amdgcn_mfma_f32_16x16x32_bf16(af[s], bf, a, 0, 0, 0);
        }
        #pragma unroll
        for (int rr = 0; rr < 4; ++rr)
            S[w][quad * 4 + rr][nt * 16 + l15] = bfb(silu_f(a[rr] + nb1v[nt]));
    }
    WFENCE();

    // GEMM2: [16x64] @ nW2[64x64] -> h (no act)
    bf16x8 a2[2];
    #pragma unroll
    for (int s = 0; s < 2; ++s)
        a2[s] = *(const bf16x8*)&S[w][l15][s * 32 + quad * 8];
    #pragma unroll
    for (int nt = 0; nt < 4; ++nt) {
        f32x4 m = {0.f, 0.f, 0.f, 0.f};
        #pragma unroll
        for (int s = 0; s < 2; ++s) {
            bf16x8 bf = *(const bf16x8*)(nw2b + ((s * 4 + nt) * 64 + lane) * 8);
            m = __builtin_amdgcn_mfma_f32_16x16x32_bf16(a2[s], bf, m, 0, 0, 0);
        }
        #pragma unroll
        for (int rr = 0; rr < 4; ++rr) {
            const float v = m[rr] + nb2v[nt];
            const size_t nd = (size_t)(t * 16 + quad * 4 + rr) * HH + nt * 16 + l15;
            h[nd] = v;
            hb[nd] = bfb(v);
        }
    }
}

extern "C" void kernel_launch(void* const* d_in, const int* in_sizes, int n_in,
                              void* d_out, int out_size, void* d_ws, size_t ws_size,
                              hipStream_t stream) {
    const float* x_in  = (const float*)d_in[0];
    const float* h_in  = (const float*)d_in[1];
    const int*   row   = (const int*)d_in[2];
    const int*   col   = (const int*)d_in[3];
    const float* efea  = (const float*)d_in[4];
    const float* emb_W = (const float*)d_in[5];
    const float* emb_b = (const float*)d_in[6];
    const float* eW1   = (const float*)d_in[7];
    const float* eb1   = (const float*)d_in[8];
    const float* eW2   = (const float*)d_in[9];
    const float* eb2   = (const float*)d_in[10];
    const float* cW1   = (const float*)d_in[11];
    const float* cb1   = (const float*)d_in[12];
    const float* cW2   = (const float*)d_in[13];
    const float* cb2   = (const float*)d_in[14];
    const float* nW1   = (const float*)d_in[15];
    const float* nb1   = (const float*)d_in[16];
    const float* nW2   = (const float*)d_in[17];
    const float* nb2   = (const float*)d_in[18];

    float* out = (float*)d_out;
    float* xo = out;                 // N*3
    float* ho = out + NN * 3;        // N*64

    // workspace layout (16B-aligned segments)
    char* wsb = (char*)d_ws;
    float* sum_f = (float*)wsb;                                  //    600,000 B
    unsigned short* tmsgb = (unsigned short*)(wsb + 600000);     //  6,400,000 B
    unsigned short* efs = (unsigned short*)(wsb + 7000000);      // 12,800,000 B
    unsigned short* hb  = (unsigned short*)(wsb + 19800000);     //  6,400,000 B
    unsigned short* wsW = (unsigned short*)(wsb + 26200000);     //    122,880 B
    int* deg    = (int*)(wsb + 26322880);                        //    200,000 B
    int* cur    = (int*)(wsb + 26522880);                        //    200,000 B
    int2* rc    = (int2*)(wsb + 26722880);                       //  6,400,000 B
    float* x4   = (float*)(wsb + 33122880);                      //    800,000 B
    int* bsum   = (int*)(wsb + 33922880);                        //        800 B
    int* boff   = (int*)(wsb + 33923680);                        //        800 B

    // zero deg, then fused setup (hist + swizzle + embed + zero + x copies)
    hipMemsetAsync(deg, 0, 200000, stream);
    setup_kernel<<<17917, 256, 0, stream>>>(
        row, deg,
        eW1, eW2, cW1, nW1, nW2, wsW,
        h_in, emb_W, emb_b, ho, hb,
        wsb, x_in, xo, x4);
    // row scan + counting sort
    scanA_kernel<<<200, 256, 0, stream>>>(deg, bsum);
    scanB_kernel<<<1, 256, 0, stream>>>(bsum, boff);
    scanC_kernel<<<200, 256, 0, stream>>>(deg, boff, cur);
    fill_kernel<<<MM / 256, 256, 0, stream>>>(row, col, efea, cur, rc, efs);

    for (int i = 0; i < 2; ++i) {
        const unsigned short* L = wsW + i * 30720;
        edge_mfma_kernel<<<NB_EDGE, 256, 0, stream>>>(
            x4, hb, rc, efs,
            L, L + 10240, L + 14336,
            eb1 + i * 64, eb2 + i * 64, cb1 + i * 64, cW2 + i * 64, cb2 + i,
            sum_f, tmsgb);
        node_mfma_kernel<<<(NN / 16 + 3) / 4, 256, 0, stream>>>(
            xo, x4, ho, hb, sum_f, deg, tmsgb,
            L + 18432, L + 26624, nb1 + i * 64, nb2 + i * 64);
    }
}

// Round 4
// 426.497 us; speedup vs baseline: 1.3282x; 1.3282x over previous
//
#include <hip/hip_runtime.h>
#include <math.h>

#define NN 50000
#define MM 800000
#define HH 64
#define NB_EDGE 1792
#define NTILE 12500                 // MM / 64 edges per block-tile

typedef short bf16x8 __attribute__((ext_vector_type(8)));
typedef float f32x4  __attribute__((ext_vector_type(4)));

// per-wave LDS fence: all LDS regions are wave-private; lockstep + lgkmcnt
// drain replaces __syncthreads
#define WFENCE() asm volatile("s_waitcnt lgkmcnt(0)" ::: "memory")

__device__ __forceinline__ float silu_f(float v) {
    return v * __builtin_amdgcn_rcpf(1.0f + __expf(-v));
}
// round-half-up fp32 -> bf16 bits (0.5 ulp max)
__device__ __forceinline__ unsigned short bfb(float a) {
    return (unsigned short)((__float_as_uint(a) + 0x8000u) >> 16);
}
// pack two f32 -> bf16x2 via v_perm (low = a, high = b)
__device__ __forceinline__ unsigned pk2(float a, float b) {
    return __builtin_amdgcn_perm(__float_as_uint(b) + 0x8000u,
                                 __float_as_uint(a) + 0x8000u, 0x07060302u);
}
__device__ __forceinline__ float b2f(unsigned short s) {
    return __uint_as_float((unsigned)s << 16);
}
// packed bf16x2 atomic add
__device__ __forceinline__ void atomic_pk_bf16(unsigned short* addr, unsigned pk) {
    asm volatile("global_atomic_pk_add_bf16 %0, %1, off"
                 :: "v"((unsigned long long)(size_t)addr), "v"(pk) : "memory");
}

// ---------------- fused setup ----------------
// blocks [0,3125): deg histogram
// blocks [3125,3365): weight pre-swizzle (per layer 30720 shorts)
// blocks [3365,15865): embedding
// blocks [15865,17574): zero sum_f+tmsgb (7,000,000 B)
// blocks [17574,17721): copy x_in -> xo (uint4)
// blocks [17721,17917): build padded x4 mirror
__global__ __launch_bounds__(256) void setup_kernel(
    const int* __restrict__ row, int* __restrict__ deg,
    const float* __restrict__ eW1, const float* __restrict__ eW2,
    const float* __restrict__ cW1, const float* __restrict__ nW1,
    const float* __restrict__ nW2, unsigned short* __restrict__ wsW,
    const float* __restrict__ h_in, const float* __restrict__ emb_W,
    const float* __restrict__ emb_b, float* __restrict__ h_out,
    unsigned short* __restrict__ hb,
    char* __restrict__ zbase, const float* __restrict__ x_in,
    float* __restrict__ xo, float* __restrict__ x4)
{
    const int b = blockIdx.x;
    if (b < 3125) {
        const int e = b * 256 + threadIdx.x;
        atomicAdd(&deg[row[e]], 1);
    } else if (b < 3365) {
        const int i = (b - 3125) * 256 + threadIdx.x;     // 0 .. 61439
        const int layer = i / 30720;
        const int rem = i - layer * 30720;
        float val;
        if (rem < 10240) {
            const int j = rem & 7, lane = (rem >> 3) & 63, nt = (rem >> 9) & 3, s = rem >> 11;
            const int kp = s * 32 + ((lane >> 4) << 3) + j;
            const int n  = nt * 16 + (lane & 15);
            if (kp > 136) val = 0.0f;
            else {
                const int k = (kp == 136) ? 0 : kp + 1;   // k'=136 is the r2 row
                val = eW1[layer * 137 * 64 + k * 64 + n];
            }
        } else if (rem < 14336) {
            const int r2 = rem - 10240;
            const int j = r2 & 7, lane = (r2 >> 3) & 63, nt = (r2 >> 9) & 3, s = r2 >> 11;
            val = eW2[layer * 4096 + (s * 32 + ((lane >> 4) << 3) + j) * 64 + nt * 16 + (lane & 15)];
        } else if (rem < 18432) {
            const int r3 = rem - 14336;
            const int j = r3 & 7, lane = (r3 >> 3) & 63, nt = (r3 >> 9) & 3, s = r3 >> 11;
            val = cW1[layer * 4096 + (s * 32 + ((lane >> 4) << 3) + j) * 64 + nt * 16 + (lane & 15)];
        } else if (rem < 26624) {
            const int r4 = rem - 18432;
            const int j = r4 & 7, lane = (r4 >> 3) & 63, nt = (r4 >> 9) & 3, s = r4 >> 11;
            const int kp = s * 32 + ((lane >> 4) << 3) + j;      // < 128
            val = nW1[layer * 8192 + kp * 64 + nt * 16 + (lane & 15)];
        } else {
            const int r5 = rem - 26624;
            const int j = r5 & 7, lane = (r5 >> 3) & 63, nt = (r5 >> 9) & 3, s = r5 >> 11;
            val = nW2[layer * 4096 + (s * 32 + ((lane >> 4) << 3) + j) * 64 + nt * 16 + (lane & 15)];
        }
        wsW[i] = bfb(val);
    } else if (b < 15865) {
        const int idx = (b - 3365) * 256 + threadIdx.x;   // over N*64
        const int n = idx >> 6, j = idx & 63;
        float acc = emb_b[j];
        #pragma unroll
        for (int k = 0; k < 16; ++k)
            acc += h_in[n * 16 + k] * emb_W[k * HH + j];
        h_out[idx] = acc;
        hb[idx] = bfb(acc);
    } else if (b < 17574) {
        const int t = (b - 15865) * 256 + threadIdx.x;
        if (t < 437500) {                                  // 7,000,000 / 16
            const uint4 z = {0u, 0u, 0u, 0u};
            *(uint4*)(zbase + (size_t)t * 16) = z;
        }
    } else if (b < 17721) {
        const int t = (b - 17574) * 256 + threadIdx.x;
        if (t < 37500)                                     // N*3 floats / 4
            ((uint4*)xo)[t] = ((const uint4*)x_in)[t];
    } else {
        const int n = (b - 17721) * 256 + threadIdx.x;
        if (n < NN) {
            float4 v;
            v.x = x_in[3 * n + 0];
            v.y = x_in[3 * n + 1];
            v.z = x_in[3 * n + 2];
            v.w = 0.0f;
            ((float4*)x4)[n] = v;
        }
    }
}

// parallel scan over NN, phase A: 200 blocks x 250-node chunks -> blocksum
__global__ __launch_bounds__(256) void scanA_kernel(const int* __restrict__ deg,
                                                    int* __restrict__ bsum) {
    __shared__ int ps[256];
    const int t = threadIdx.x;
    const int base = blockIdx.x * 250;
    int v = (t < 250) ? deg[base + t] : 0;
    ps[t] = v;
    __syncthreads();
    for (int off = 1; off < 256; off <<= 1) {
        const int u = (t >= off) ? ps[t - off] : 0;
        __syncthreads();
        ps[t] += u;
        __syncthreads();
    }
    if (t == 255) bsum[blockIdx.x] = ps[255];
}

// phase B: exclusive scan of 200 blocksums (single small block)
__global__ __launch_bounds__(256) void scanB_kernel(const int* __restrict__ bsum,
                                                    int* __restrict__ boff) {
    __shared__ int ps[256];
    const int t = threadIdx.x;
    int v = (t < 200) ? bsum[t] : 0;
    ps[t] = v;
    __syncthreads();
    for (int off = 1; off < 256; off <<= 1) {
        const int u = (t >= off) ? ps[t - off] : 0;
        __syncthreads();
        ps[t] += u;
        __syncthreads();
    }
    if (t < 200) boff[t] = ps[t] - v;     // exclusive
}

// phase C: per-chunk exclusive scan + global offset -> cur
__global__ __launch_bounds__(256) void scanC_kernel(const int* __restrict__ deg,
                                                    const int* __restrict__ boff,
                                                    int* __restrict__ cur) {
    __shared__ int ps[256];
    const int t = threadIdx.x;
    const int base = blockIdx.x * 250;
    int v = (t < 250) ? deg[base + t] : 0;
    ps[t] = v;
    __syncthreads();
    for (int off = 1; off < 256; off <<= 1) {
        const int u = (t >= off) ? ps[t - off] : 0;
        __syncthreads();
        ps[t] += u;
        __syncthreads();
    }
    if (t < 250)
        cur[base + t] = boff[blockIdx.x] + ps[t] - v;   // exclusive prefix
}

// one-pass counting-sort fill: rc (int2 interleaved) + efs in row-sorted order
__global__ __launch_bounds__(256) void fill_kernel(
    const int* __restrict__ row, const int* __restrict__ col,
    const float* __restrict__ efea, int* __restrict__ cur,
    int2* __restrict__ rc, unsigned short* __restrict__ efs)
{
    const int e = blockIdx.x * 256 + threadIdx.x;
    const int r = row[e];
    const int pos = atomicAdd(&cur[r], 1);
    int2 v; v.x = r; v.y = col[e];
    rc[pos] = v;                                       // one 8B scatter
    const float4* ef = (const float4*)(efea + (size_t)e * 8);
    const float4 e0 = ef[0], e1 = ef[1];
    uint4 ue = { pk2(e0.x, e0.y), pk2(e0.z, e0.w), pk2(e1.x, e1.y), pk2(e1.z, e1.w) };
    *(uint4*)(efs + (size_t)pos * 8) = ue;
}

// ---------------- MFMA edge kernel: 16 sorted edges per wave ----------------
// GEMM1 A-fragments load DIRECTLY from global into registers (no LDS staging):
// lane (l15,quad) needs hb[r(l15)]*64 + s*32 + quad*8 -- a 16B load. Slice 4
// (efs | r2 | zero-pad) is assembled in-register: quad0 = efs load, quad1 = r2
// from x4 (computes RV as side effect), quads 2-3 = zero. This deletes the
// whole LDS input region, 8 ds_writes + 5 ds_reads + 2 fences per iteration.
// w1f keeps slices 0..3 in AGPRs (64); slice-4 B-frags live in WS LDS
// (uint4 [1024,1280) of w1b), keeping VGPR+AGPR <= 128 for 4 waves/SIMD.
// S rows padded to 72 shorts = 144 B so bf16x8 LDS reads stay 16B-aligned.
__global__ __launch_bounds__(256, 4) void edge_mfma_kernel(
    const float* __restrict__ x4, const unsigned short* __restrict__ hb,
    const int2* __restrict__ rc, const unsigned short* __restrict__ efs,
    const unsigned short* __restrict__ w1b, const unsigned short* __restrict__ w2b,
    const unsigned short* __restrict__ cw1b,
    const float* __restrict__ b1, const float* __restrict__ b2,
    const float* __restrict__ cb1, const float* __restrict__ cw2,
    const float* __restrict__ cb2,
    float* __restrict__ sum_f, unsigned short* __restrict__ tmsgb)
{
    __shared__ __align__(16) unsigned short S[4][16][72];   // [0,64)=H1/msg, [64,66)=cm f32
    __shared__ float RV[4][16][4];
    __shared__ int   RI[4][16];
    __shared__ __align__(16) unsigned short WS[10240];
    // WS shorts: [0,4096)=w2b  [4096,8192)=cw1b  [8192,10240)=w1 slice4

    const int tid = threadIdx.x;
    const int w = tid >> 6, lane = tid & 63;
    const int l15 = lane & 15, quad = lane >> 4;

    // stage GEMM2/GEMM3 + W1-slice4 weights into LDS, block-shared
    {
        const uint4* s2 = (const uint4*)w2b;
        const uint4* s3 = (const uint4*)cw1b;
        const uint4* s4 = (const uint4*)w1b;   // slice4 = uint4 idx [1024,1280)
        uint4* dst = (uint4*)WS;
        dst[tid]        = s2[tid];
        dst[256 + tid]  = s2[256 + tid];
        dst[512 + tid]  = s3[tid];
        dst[768 + tid]  = s3[256 + tid];
        dst[1024 + tid] = s4[1024 + tid];
    }

    // hoist W1 slices 0..3 into registers (loop-invariant; AGPR-parked, 64)
    bf16x8 w1f[4][4];
    #pragma unroll
    for (int s = 0; s < 4; ++s)
        #pragma unroll
        for (int nt = 0; nt < 4; ++nt)
            w1f[s][nt] = *(const bf16x8*)(w1b + ((s * 4 + nt) * 64 + lane) * 8);

    float b1v[4], b2v[4], cb1v[4], cw2v[4];
    #pragma unroll
    for (int nt = 0; nt < 4; ++nt) {
        b1v[nt]  = b1[nt * 16 + l15];
        b2v[nt]  = b2[nt * 16 + l15];
        cb1v[nt] = cb1[nt * 16 + l15];
        cw2v[nt] = cw2[nt * 16 + l15];
    }
    const float cb2s = cb2[0];

    __syncthreads();   // WS visible to all 4 waves

    for (int bt = blockIdx.x; bt < NTILE; bt += NB_EDGE) {
        const int t = bt * 4 + w;
        const int p = t * 16 + l15;          // this lane's edge (shared by 4 quads)
        const int2 rcv = rc[p];
        const int r = rcv.x, c = rcv.y;

        // ---- direct A-fragment gather ----
        const unsigned short* hr = hb + (size_t)r * HH + quad * 8;
        const unsigned short* hc = hb + (size_t)c * HH + quad * 8;
        bf16x8 af0 = *(const bf16x8*)(hr);
        bf16x8 af1 = *(const bf16x8*)(hr + 32);
        bf16x8 af2 = *(const bf16x8*)(hc);
        bf16x8 af3 = *(const bf16x8*)(hc + 32);
        bf16x8 af4 = {0, 0, 0, 0, 0, 0, 0, 0};
        if (quad == 0) {
            af4 = *(const bf16x8*)(efs + (size_t)p * 8);
            RI[w][l15] = r;
        } else if (quad == 1) {
            const float4 xr = ((const float4*)x4)[r];
            const float4 xc = ((const float4*)x4)[c];
            const float rx = xr.x - xc.x;
            const float ry = xr.y - xc.y;
            const float rz = xr.z - xc.z;
            RV[w][l15][0] = rx; RV[w][l15][1] = ry; RV[w][l15][2] = rz;
            af4[0] = (short)bfb(rx * rx + ry * ry + rz * rz);
        }

        // ---- GEMM1: [16x160] @ W1 -> H1 (S cols 0..63) ----
        #pragma unroll
        for (int nt = 0; nt < 4; ++nt) {
            f32x4 a = {0.f, 0.f, 0.f, 0.f};
            a = __builtin_amdgcn_mfma_f32_16x16x32_bf16(af0, w1f[0][nt], a, 0, 0, 0);
            a = __builtin_amdgcn_mfma_f32_16x16x32_bf16(af1, w1f[1][nt], a, 0, 0, 0);
            a = __builtin_amdgcn_mfma_f32_16x16x32_bf16(af2, w1f[2][nt], a, 0, 0, 0);
            a = __builtin_amdgcn_mfma_f32_16x16x32_bf16(af3, w1f[3][nt], a, 0, 0, 0);
            {
                bf16x8 b4 = *(const bf16x8*)&WS[8192 + (nt * 64 + lane) * 8];
                a = __builtin_amdgcn_mfma_f32_16x16x32_bf16(af4, b4, a, 0, 0, 0);
            }
            #pragma unroll
            for (int rr = 0; rr < 4; ++rr)
                S[w][quad * 4 + rr][nt * 16 + l15] = bfb(silu_f(a[rr] + b1v[nt]));
        }
        WFENCE();

        // ---- GEMM2: H1 @ W2 -> msg (alias back into cols 0..63) ----
        bf16x8 a2[2];
        #pragma unroll
        for (int s = 0; s < 2; ++s)
            a2[s] = *(const bf16x8*)&S[w][l15][s * 32 + quad * 8];
        WFENCE();   // a2 in regs before msg overwrites
        #pragma unroll
        for (int nt = 0; nt < 4; ++nt) {
            f32x4 m = {0.f, 0.f, 0.f, 0.f};
            #pragma unroll
            for (int s = 0; s < 2; ++s) {
                bf16x8 bf = *(const bf16x8*)&WS[((s * 4 + nt) * 64 + lane) * 8];
                m = __builtin_amdgcn_mfma_f32_16x16x32_bf16(a2[s], bf, m, 0, 0, 0);
            }
            #pragma unroll
            for (int rr = 0; rr < 4; ++rr)
                S[w][quad * 4 + rr][nt * 16 + l15] = bfb(silu_f(m[rr] + b2v[nt]));
        }
        WFENCE();

        // ---- GEMM3: msg @ cW1 -> c1; dot cW2 -> cm (S col 64 as f32) ----
        bf16x8 a3[2];
        #pragma unroll
        for (int s = 0; s < 2; ++s)
            a3[s] = *(const bf16x8*)&S[w][l15][s * 32 + quad * 8];
        float pr[4] = {0.f, 0.f, 0.f, 0.f};
        #pragma unroll
        for (int nt = 0; nt < 4; ++nt) {
            f32x4 q = {0.f, 0.f, 0.f, 0.f};
            #pragma unroll
            for (int s = 0; s < 2; ++s) {
                bf16x8 bf = *(const bf16x8*)&WS[4096 + ((s * 4 + nt) * 64 + lane) * 8];
                q = __builtin_amdgcn_mfma_f32_16x16x32_bf16(a3[s], bf, q, 0, 0, 0);
            }
            #pragma unroll
            for (int rr = 0; rr < 4; ++rr)
                pr[rr] += silu_f(q[rr] + cb1v[nt]) * cw2v[nt];
        }
        #pragma unroll
        for (int rr = 0; rr < 4; ++rr) {
            float tt = pr[rr];
            tt += __shfl_xor(tt, 1, 64);
            tt += __shfl_xor(tt, 2, 64);
            tt += __shfl_xor(tt, 4, 64);
            tt += __shfl_xor(tt, 8, 64);
            if (l15 == 0) *(float*)&S[w][quad * 4 + rr][64] = tt + cb2s;
        }
        WFENCE();

        // ---- segmented flush: rows sorted by RI within the tile ----
        if (lane < 32) {   // msg -> tmsgb: lane owns cols {2l, 2l+1}, pk atomic
            unsigned both = *(const unsigned*)&S[w][0][2 * lane];
            float ax = b2f((unsigned short)(both & 0xffffu));
            float ay = b2f((unsigned short)(both >> 16));
            int cur_r = RI[w][0];
            #pragma unroll
            for (int g = 1; g < 16; ++g) {
                const int ri = RI[w][g];
                unsigned bv = *(const unsigned*)&S[w][g][2 * lane];
                const float vx = b2f((unsigned short)(bv & 0xffffu));
                const float vy = b2f((unsigned short)(bv >> 16));
                if (ri != cur_r) {
                    atomic_pk_bf16(&tmsgb[(size_t)cur_r * HH + 2 * lane], pk2(ax, ay));
                    ax = 0.f; ay = 0.f; cur_r = ri;
                }
                ax += vx; ay += vy;
            }
            atomic_pk_bf16(&tmsgb[(size_t)cur_r * HH + 2 * lane], pk2(ax, ay));
        } else if ((lane & 31) < 3) {   // f = rij*cm -> sum_f (fp32, tiny)
            const int sl = lane & 31;
            float acc = RV[w][0][sl] * (*(const float*)&S[w][0][64]);
            int cur_r = RI[w][0];
            #pragma unroll
            for (int g = 1; g < 16; ++g) {
                const int ri = RI[w][g];
                const float v = RV[w][g][sl] * (*(const float*)&S[w][g][64]);
                if (ri != cur_r) {
                    atomicAdd(&sum_f[3 * cur_r + sl], acc);
                    acc = 0.f; cur_r = ri;
                }
                acc += v;
            }
            atomicAdd(&sum_f[3 * cur_r + sl], acc);
        }
        WFENCE();   // flush reads drained before next iter's S writes (WAR)
    }
}

// ---------------- MFMA node kernel: 16 nodes per wave ----------------
// Reads bf16 tmsgb directly; zeroes tmsgb/sum_f after use (next layer's init).
// Updates both xo (output) and x4 (padded mirror for next layer's edge pass).
__global__ __launch_bounds__(256) void node_mfma_kernel(
    float* __restrict__ x, float* __restrict__ x4, float* __restrict__ h,
    unsigned short* __restrict__ hb,
    float* __restrict__ sum_f, const int* __restrict__ deg,
    unsigned short* __restrict__ tmsgb,
    const unsigned short* __restrict__ nw1b, const unsigned short* __restrict__ nw2b,
    const float* __restrict__ nb1, const float* __restrict__ nb2)
{
    __shared__ __align__(16) unsigned short S[4][16][136];
    const int tid = threadIdx.x;
    const int w = tid >> 6, lane = tid & 63;
    const int l15 = lane & 15, quad = lane >> 4;
    const int le = lane >> 2, sub = lane & 3;
    const int t = blockIdx.x * 4 + w;
    if (t >= NN / 16) return;                      // 3125 waves exactly

    // gather (fully coalesced): [hb | tmsgb] -> S[16][128]; zero tmsgb after
    {
        unsigned short* Srow = &S[w][le][0];
        const int n = t * 16 + le;
        const unsigned short* hr = hb + (size_t)n * HH + sub * 16;
        *(uint4*)&Srow[sub * 16]     = *(const uint4*)(hr);
        *(uint4*)&Srow[sub * 16 + 8] = *(const uint4*)(hr + 8);
        unsigned short* tm = tmsgb + (size_t)n * HH + sub * 16;
        *(uint4*)&Srow[64 + sub * 16]     = *(const uint4*)(tm);
        *(uint4*)&Srow[64 + sub * 16 + 8] = *(const uint4*)(tm + 8);
        const uint4 z = {0u, 0u, 0u, 0u};
        *(uint4*)(tm)     = z;
        *(uint4*)(tm + 8) = z;
    }
    // x update: one lane per node; zero sum_f after
    if (lane < 16) {
        const int nn = t * 16 + lane;
        const float cn = fmaxf((float)deg[nn], 1.0f);
        const float rc = __builtin_amdgcn_rcpf(cn);
        #pragma unroll
        for (int d3 = 0; d3 < 3; ++d3) {
            float tf = sum_f[3 * nn + d3] * rc;
            tf = fminf(fmaxf(tf, -100.0f), 100.0f);
            x[3 * nn + d3] += tf;
            x4[4 * nn + d3] += tf;
            sum_f[3 * nn + d3] = 0.0f;
        }
    }
    WFENCE();

    // GEMM1: [16x128] @ nW1[128x64] -> SiLU -> alias cols 0..63
    bf16x8 af[4];
    #pragma unroll
    for (int s = 0; s < 4; ++s)
        af[s] = *(const bf16x8*)&S[w][l15][s * 32 + quad * 8];
    WFENCE();
    float nb1v[4], nb2v[4];
    #pragma unroll
    for (int nt = 0; nt < 4; ++nt) {
        nb1v[nt] = nb1[nt * 16 + l15];
        nb2v[nt] = nb2[nt * 16 + l15];
    }
    #pragma unroll
    for (int nt = 0; nt < 4; ++nt) {
        f32x4 a = {0.f, 0.f, 0.f, 0.f};
        #pragma unroll
        for (int s = 0; s < 4; ++s) {
            bf16x8 bf = *(const bf16x8*)(nw1b + ((s * 4 + nt) * 64 + lane) * 8);
            a = __builtin_amdgcn_mfma_f32_16x16x32_bf16(af[s], bf, a, 0, 0, 0);
        }
        #pragma unroll
        for (int rr = 0; rr < 4; ++rr)
            S[w][quad * 4 + rr][nt * 16 + l15] = bfb(silu_f(a[rr] + nb1v[nt]));
    }
    WFENCE();

    // GEMM2: [16x64] @ nW2[64x64] -> h (no act)
    bf16x8 a2[2];
    #pragma unroll
    for (int s = 0; s < 2; ++s)
        a2[s] = *(const bf16x8*)&S[w][l15][s * 32 + quad * 8];
    #pragma unroll
    for (int nt = 0; nt < 4; ++nt) {
        f32x4 m = {0.f, 0.f, 0.f, 0.f};
        #pragma unroll
        for (int s = 0; s < 2; ++s) {
            bf16x8 bf = *(const bf16x8*)(nw2b + ((s * 4 + nt) * 64 + lane) * 8);
            m = __builtin_amdgcn_mfma_f32_16x16x32_bf16(a2[s], bf, m, 0, 0, 0);
        }
        #pragma unroll
        for (int rr = 0; rr < 4; ++rr) {
            const float v = m[rr] + nb2v[nt];
            const size_t nd = (size_t)(t * 16 + quad * 4 + rr) * HH + nt * 16 + l15;
            h[nd] = v;
            hb[nd] = bfb(v);
        }
    }
}

extern "C" void kernel_launch(void* const* d_in, const int* in_sizes, int n_in,
                              void* d_out, int out_size, void* d_ws, size_t ws_size,
                              hipStream_t stream) {
    const float* x_in  = (const float*)d_in[0];
    const float* h_in  = (const float*)d_in[1];
    const int*   row   = (const int*)d_in[2];
    const int*   col   = (const int*)d_in[3];
    const float* efea  = (const float*)d_in[4];
    const float* emb_W = (const float*)d_in[5];
    const float* emb_b = (const float*)d_in[6];
    const float* eW1   = (const float*)d_in[7];
    const float* eb1   = (const float*)d_in[8];
    const float* eW2   = (const float*)d_in[9];
    const float* eb2   = (const float*)d_in[10];
    const float* cW1   = (const float*)d_in[11];
    const float* cb1   = (const float*)d_in[12];
    const float* cW2   = (const float*)d_in[13];
    const float* cb2   = (const float*)d_in[14];
    const float* nW1   = (const float*)d_in[15];
    const float* nb1   = (const float*)d_in[16];
    const float* nW2   = (const float*)d_in[17];
    const float* nb2   = (const float*)d_in[18];

    float* out = (float*)d_out;
    float* xo = out;                 // N*3
    float* ho = out + NN * 3;        // N*64

    // workspace layout (16B-aligned segments)
    char* wsb = (char*)d_ws;
    float* sum_f = (float*)wsb;                                  //    600,000 B
    unsigned short* tmsgb = (unsigned short*)(wsb + 600000);     //  6,400,000 B
    unsigned short* efs = (unsigned short*)(wsb + 7000000);      // 12,800,000 B
    unsigned short* hb  = (unsigned short*)(wsb + 19800000);     //  6,400,000 B
    unsigned short* wsW = (unsigned short*)(wsb + 26200000);     //    122,880 B
    int* deg    = (int*)(wsb + 26322880);                        //    200,000 B
    int* cur    = (int*)(wsb + 26522880);                        //    200,000 B
    int2* rc    = (int2*)(wsb + 26722880);                       //  6,400,000 B
    float* x4   = (float*)(wsb + 33122880);                      //    800,000 B
    int* bsum   = (int*)(wsb + 33922880);                        //        800 B
    int* boff   = (int*)(wsb + 33923680);                        //        800 B

    // zero deg, then fused setup (hist + swizzle + embed + zero + x copies)
    hipMemsetAsync(deg, 0, 200000, stream);
    setup_kernel<<<17917, 256, 0, stream>>>(
        row, deg,
        eW1, eW2, cW1, nW1, nW2, wsW,
        h_in, emb_W, emb_b, ho, hb,
        wsb, x_in, xo, x4);
    // row scan + counting sort
    scanA_kernel<<<200, 256, 0, stream>>>(deg, bsum);
    scanB_kernel<<<1, 256, 0, stream>>>(bsum, boff);
    scanC_kernel<<<200, 256, 0, stream>>>(deg, boff, cur);
    fill_kernel<<<MM / 256, 256, 0, stream>>>(row, col, efea, cur, rc, efs);

    for (int i = 0; i < 2; ++i) {
        const unsigned short* L = wsW + i * 30720;
        edge_mfma_kernel<<<NB_EDGE, 256, 0, stream>>>(
            x4, hb, rc, efs,
            L, L + 10240, L + 14336,
            eb1 + i * 64, eb2 + i * 64, cb1 + i * 64, cW2 + i * 64, cb2 + i,
            sum_f, tmsgb);
        node_mfma_kernel<<<(NN / 16 + 3) / 4, 256, 0, stream>>>(
            xo, x4, ho, hb, sum_f, deg, tmsgb,
            L + 18432, L + 26624, nb1 + i * 64, nb2 + i * 64);
    }
}

// Round 5
// 426.416 us; speedup vs baseline: 1.3285x; 1.0002x over previous
//
#include <hip/hip_runtime.h>
#include <math.h>

#define NN 50000
#define MM 800000
#define HH 64
#define NB_EDGE 768
#define NTILE 12500                 // MM / 64 edges per block-tile

typedef short bf16x8 __attribute__((ext_vector_type(8)));
typedef float f32x4  __attribute__((ext_vector_type(4)));

// per-wave LDS fence: all LDS regions are wave-private; lockstep + lgkmcnt
// drain replaces __syncthreads
#define WFENCE() asm volatile("s_waitcnt lgkmcnt(0)" ::: "memory")

__device__ __forceinline__ float silu_f(float v) {
    return v * __builtin_amdgcn_rcpf(1.0f + __expf(-v));
}
// round-half-up fp32 -> bf16 bits (0.5 ulp max)
__device__ __forceinline__ unsigned short bfb(float a) {
    return (unsigned short)((__float_as_uint(a) + 0x8000u) >> 16);
}
// pack two f32 -> bf16x2 via v_perm (low = a, high = b)
__device__ __forceinline__ unsigned pk2(float a, float b) {
    return __builtin_amdgcn_perm(__float_as_uint(b) + 0x8000u,
                                 __float_as_uint(a) + 0x8000u, 0x07060302u);
}
__device__ __forceinline__ float b2f(unsigned short s) {
    return __uint_as_float((unsigned)s << 16);
}
// packed bf16x2 atomic add
__device__ __forceinline__ void atomic_pk_bf16(unsigned short* addr, unsigned pk) {
    asm volatile("global_atomic_pk_add_bf16 %0, %1, off"
                 :: "v"((unsigned long long)(size_t)addr), "v"(pk) : "memory");
}

// ---------------- fused setup ----------------
// blocks [0,3125): deg histogram
// blocks [3125,3365): weight pre-swizzle (per layer 30720 shorts)
// blocks [3365,15865): embedding
// blocks [15865,17574): zero sum_f+tmsgb (7,000,000 B)
// blocks [17574,17721): copy x_in -> xo (uint4)
// blocks [17721,17917): build padded x4 mirror
__global__ __launch_bounds__(256) void setup_kernel(
    const int* __restrict__ row, int* __restrict__ deg,
    const float* __restrict__ eW1, const float* __restrict__ eW2,
    const float* __restrict__ cW1, const float* __restrict__ nW1,
    const float* __restrict__ nW2, unsigned short* __restrict__ wsW,
    const float* __restrict__ h_in, const float* __restrict__ emb_W,
    const float* __restrict__ emb_b, float* __restrict__ h_out,
    unsigned short* __restrict__ hb,
    char* __restrict__ zbase, const float* __restrict__ x_in,
    float* __restrict__ xo, float* __restrict__ x4)
{
    const int b = blockIdx.x;
    if (b < 3125) {
        const int e = b * 256 + threadIdx.x;
        atomicAdd(&deg[row[e]], 1);
    } else if (b < 3365) {
        const int i = (b - 3125) * 256 + threadIdx.x;     // 0 .. 61439
        const int layer = i / 30720;
        const int rem = i - layer * 30720;
        float val;
        if (rem < 10240) {
            const int j = rem & 7, lane = (rem >> 3) & 63, nt = (rem >> 9) & 3, s = rem >> 11;
            const int kp = s * 32 + ((lane >> 4) << 3) + j;
            const int n  = nt * 16 + (lane & 15);
            if (kp > 136) val = 0.0f;
            else {
                const int k = (kp == 136) ? 0 : kp + 1;   // k'=136 is the r2 row
                val = eW1[layer * 137 * 64 + k * 64 + n];
            }
        } else if (rem < 14336) {
            const int r2 = rem - 10240;
            const int j = r2 & 7, lane = (r2 >> 3) & 63, nt = (r2 >> 9) & 3, s = r2 >> 11;
            val = eW2[layer * 4096 + (s * 32 + ((lane >> 4) << 3) + j) * 64 + nt * 16 + (lane & 15)];
        } else if (rem < 18432) {
            const int r3 = rem - 14336;
            const int j = r3 & 7, lane = (r3 >> 3) & 63, nt = (r3 >> 9) & 3, s = r3 >> 11;
            val = cW1[layer * 4096 + (s * 32 + ((lane >> 4) << 3) + j) * 64 + nt * 16 + (lane & 15)];
        } else if (rem < 26624) {
            const int r4 = rem - 18432;
            const int j = r4 & 7, lane = (r4 >> 3) & 63, nt = (r4 >> 9) & 3, s = r4 >> 11;
            const int kp = s * 32 + ((lane >> 4) << 3) + j;      // < 128
            val = nW1[layer * 8192 + kp * 64 + nt * 16 + (lane & 15)];
        } else {
            const int r5 = rem - 26624;
            const int j = r5 & 7, lane = (r5 >> 3) & 63, nt = (r5 >> 9) & 3, s = r5 >> 11;
            val = nW2[layer * 4096 + (s * 32 + ((lane >> 4) << 3) + j) * 64 + nt * 16 + (lane & 15)];
        }
        wsW[i] = bfb(val);
    } else if (b < 15865) {
        const int idx = (b - 3365) * 256 + threadIdx.x;   // over N*64
        const int n = idx >> 6, j = idx & 63;
        float acc = emb_b[j];
        #pragma unroll
        for (int k = 0; k < 16; ++k)
            acc += h_in[n * 16 + k] * emb_W[k * HH + j];
        h_out[idx] = acc;
        hb[idx] = bfb(acc);
    } else if (b < 17574) {
        const int t = (b - 15865) * 256 + threadIdx.x;
        if (t < 437500) {                                  // 7,000,000 / 16
            const uint4 z = {0u, 0u, 0u, 0u};
            *(uint4*)(zbase + (size_t)t * 16) = z;
        }
    } else if (b < 17721) {
        const int t = (b - 17574) * 256 + threadIdx.x;
        if (t < 37500)                                     // N*3 floats / 4
            ((uint4*)xo)[t] = ((const uint4*)x_in)[t];
    } else {
        const int n = (b - 17721) * 256 + threadIdx.x;
        if (n < NN) {
            float4 v;
            v.x = x_in[3 * n + 0];
            v.y = x_in[3 * n + 1];
            v.z = x_in[3 * n + 2];
            v.w = 0.0f;
            ((float4*)x4)[n] = v;
        }
    }
}

// parallel scan over NN, phase A: 200 blocks x 250-node chunks -> blocksum
__global__ __launch_bounds__(256) void scanA_kernel(const int* __restrict__ deg,
                                                    int* __restrict__ bsum) {
    __shared__ int ps[256];
    const int t = threadIdx.x;
    const int base = blockIdx.x * 250;
    int v = (t < 250) ? deg[base + t] : 0;
    ps[t] = v;
    __syncthreads();
    for (int off = 1; off < 256; off <<= 1) {
        const int u = (t >= off) ? ps[t - off] : 0;
        __syncthreads();
        ps[t] += u;
        __syncthreads();
    }
    if (t == 255) bsum[blockIdx.x] = ps[255];
}

// phase B: exclusive scan of 200 blocksums (single small block)
__global__ __launch_bounds__(256) void scanB_kernel(const int* __restrict__ bsum,
                                                    int* __restrict__ boff) {
    __shared__ int ps[256];
    const int t = threadIdx.x;
    int v = (t < 200) ? bsum[t] : 0;
    ps[t] = v;
    __syncthreads();
    for (int off = 1; off < 256; off <<= 1) {
        const int u = (t >= off) ? ps[t - off] : 0;
        __syncthreads();
        ps[t] += u;
        __syncthreads();
    }
    if (t < 200) boff[t] = ps[t] - v;     // exclusive
}

// phase C: per-chunk exclusive scan + global offset -> cur
__global__ __launch_bounds__(256) void scanC_kernel(const int* __restrict__ deg,
                                                    const int* __restrict__ boff,
                                                    int* __restrict__ cur) {
    __shared__ int ps[256];
    const int t = threadIdx.x;
    const int base = blockIdx.x * 250;
    int v = (t < 250) ? deg[base + t] : 0;
    ps[t] = v;
    __syncthreads();
    for (int off = 1; off < 256; off <<= 1) {
        const int u = (t >= off) ? ps[t - off] : 0;
        __syncthreads();
        ps[t] += u;
        __syncthreads();
    }
    if (t < 250)
        cur[base + t] = boff[blockIdx.x] + ps[t] - v;   // exclusive prefix
}

// one-pass counting-sort fill: rc (int2 interleaved) + efs in row-sorted order
__global__ __launch_bounds__(256) void fill_kernel(
    const int* __restrict__ row, const int* __restrict__ col,
    const float* __restrict__ efea, int* __restrict__ cur,
    int2* __restrict__ rc, unsigned short* __restrict__ efs)
{
    const int e = blockIdx.x * 256 + threadIdx.x;
    const int r = row[e];
    const int pos = atomicAdd(&cur[r], 1);
    int2 v; v.x = r; v.y = col[e];
    rc[pos] = v;                                       // one 8B scatter
    const float4* ef = (const float4*)(efea + (size_t)e * 8);
    const float4 e0 = ef[0], e1 = ef[1];
    uint4 ue = { pk2(e0.x, e0.y), pk2(e0.z, e0.w), pk2(e1.x, e1.y), pk2(e1.z, e1.w) };
    *(uint4*)(efs + (size_t)pos * 8) = ue;
}

// ---------------- MFMA edge kernel: 2 tiles x 16 edges per wave (ILP-2) ----
// Direct global->register A-fragments (R4). NEW: each wave processes TWO
// independent 16-edge tiles (A = bt, B = bt+NB_EDGE) through merged phases:
// G1(A),G1(B) -> fence -> G2(A),G2(B) -> fence -> G3 -> flush(A),flush(B).
// Halves the lgkmcnt(0) drains per tile and interleaves tile B's MFMAs with
// tile A's silu epilogues (MFMA||VALU co-issue) -- attacks the ~35% idle at
// the 4-wave/SIMD register ceiling by adding ILP instead of TLP.
// w1f AGPRs are shared by both tiles. 3 waves/SIMD x 2-deep = 6 streams.
__global__ __launch_bounds__(256, 3) void edge_mfma_kernel(
    const float* __restrict__ x4, const unsigned short* __restrict__ hb,
    const int2* __restrict__ rc, const unsigned short* __restrict__ efs,
    const unsigned short* __restrict__ w1b, const unsigned short* __restrict__ w2b,
    const unsigned short* __restrict__ cw1b,
    const float* __restrict__ b1, const float* __restrict__ b2,
    const float* __restrict__ cb1, const float* __restrict__ cw2,
    const float* __restrict__ cb2,
    float* __restrict__ sum_f, unsigned short* __restrict__ tmsgb)
{
    __shared__ __align__(16) unsigned short S[2][4][16][72]; // [0,64)=H1/msg, [64,66)=cm f32
    __shared__ float RV[2][4][16][4];
    __shared__ int   RI[2][4][16];
    __shared__ __align__(16) unsigned short WS[10240];
    // WS shorts: [0,4096)=w2b  [4096,8192)=cw1b  [8192,10240)=w1 slice4

    const int tid = threadIdx.x;
    const int w = tid >> 6, lane = tid & 63;
    const int l15 = lane & 15, quad = lane >> 4;

    // stage GEMM2/GEMM3 + W1-slice4 weights into LDS, block-shared
    {
        const uint4* s2 = (const uint4*)w2b;
        const uint4* s3 = (const uint4*)cw1b;
        const uint4* s4 = (const uint4*)w1b;   // slice4 = uint4 idx [1024,1280)
        uint4* dst = (uint4*)WS;
        dst[tid]        = s2[tid];
        dst[256 + tid]  = s2[256 + tid];
        dst[512 + tid]  = s3[tid];
        dst[768 + tid]  = s3[256 + tid];
        dst[1024 + tid] = s4[1024 + tid];
    }

    // hoist W1 slices 0..3 into registers (loop-invariant; AGPR-parked, 64)
    bf16x8 w1f[4][4];
    #pragma unroll
    for (int s = 0; s < 4; ++s)
        #pragma unroll
        for (int nt = 0; nt < 4; ++nt)
            w1f[s][nt] = *(const bf16x8*)(w1b + ((s * 4 + nt) * 64 + lane) * 8);

    float b1v[4], b2v[4], cb1v[4], cw2v[4];
    #pragma unroll
    for (int nt = 0; nt < 4; ++nt) {
        b1v[nt]  = b1[nt * 16 + l15];
        b2v[nt]  = b2[nt * 16 + l15];
        cb1v[nt] = cb1[nt * 16 + l15];
        cw2v[nt] = cw2[nt * 16 + l15];
    }
    const float cb2s = cb2[0];

    __syncthreads();   // WS visible to all 4 waves

    for (int bt = blockIdx.x; bt < NTILE; bt += 2 * NB_EDGE) {
        const int btB = bt + NB_EDGE;
        const bool haveB = (btB < NTILE);
        const int btBc = haveB ? btB : bt;     // clamp: tail recomputes A, flushB skipped

        // ---- direct A-fragment gather, tiles A and B (all loads in flight) ----
        const int pA = (bt * 4 + w) * 16 + l15;
        const int pB = (btBc * 4 + w) * 16 + l15;
        const int2 rcA = rc[pA];
        const int2 rcB = rc[pB];

        const unsigned short* hrA = hb + (size_t)rcA.x * HH + quad * 8;
        const unsigned short* hcA = hb + (size_t)rcA.y * HH + quad * 8;
        bf16x8 aA0 = *(const bf16x8*)(hrA);
        bf16x8 aA1 = *(const bf16x8*)(hrA + 32);
        bf16x8 aA2 = *(const bf16x8*)(hcA);
        bf16x8 aA3 = *(const bf16x8*)(hcA + 32);
        bf16x8 aA4 = {0, 0, 0, 0, 0, 0, 0, 0};
        const unsigned short* hrB = hb + (size_t)rcB.x * HH + quad * 8;
        const unsigned short* hcB = hb + (size_t)rcB.y * HH + quad * 8;
        bf16x8 aB0 = *(const bf16x8*)(hrB);
        bf16x8 aB1 = *(const bf16x8*)(hrB + 32);
        bf16x8 aB2 = *(const bf16x8*)(hcB);
        bf16x8 aB3 = *(const bf16x8*)(hcB + 32);
        bf16x8 aB4 = {0, 0, 0, 0, 0, 0, 0, 0};
        if (quad == 0) {
            aA4 = *(const bf16x8*)(efs + (size_t)pA * 8);
            aB4 = *(const bf16x8*)(efs + (size_t)pB * 8);
            RI[0][w][l15] = rcA.x;
            RI[1][w][l15] = rcB.x;
        } else if (quad == 1) {
            const float4 xrA = ((const float4*)x4)[rcA.x];
            const float4 xcA = ((const float4*)x4)[rcA.y];
            const float rxA = xrA.x - xcA.x;
            const float ryA = xrA.y - xcA.y;
            const float rzA = xrA.z - xcA.z;
            RV[0][w][l15][0] = rxA; RV[0][w][l15][1] = ryA; RV[0][w][l15][2] = rzA;
            aA4[0] = (short)bfb(rxA * rxA + ryA * ryA + rzA * rzA);
            const float4 xrB = ((const float4*)x4)[rcB.x];
            const float4 xcB = ((const float4*)x4)[rcB.y];
            const float rxB = xrB.x - xcB.x;
            const float ryB = xrB.y - xcB.y;
            const float rzB = xrB.z - xcB.z;
            RV[1][w][l15][0] = rxB; RV[1][w][l15][1] = ryB; RV[1][w][l15][2] = rzB;
            aB4[0] = (short)bfb(rxB * rxB + ryB * ryB + rzB * rzB);
        }

        // ---- GEMM1 (A then B): [16x160] @ W1 -> H1 -> S[t] cols 0..63 ----
        #pragma unroll
        for (int nt = 0; nt < 4; ++nt) {
            f32x4 a = {0.f, 0.f, 0.f, 0.f};
            a = __builtin_amdgcn_mfma_f32_16x16x32_bf16(aA0, w1f[0][nt], a, 0, 0, 0);
            a = __builtin_amdgcn_mfma_f32_16x16x32_bf16(aA1, w1f[1][nt], a, 0, 0, 0);
            a = __builtin_amdgcn_mfma_f32_16x16x32_bf16(aA2, w1f[2][nt], a, 0, 0, 0);
            a = __builtin_amdgcn_mfma_f32_16x16x32_bf16(aA3, w1f[3][nt], a, 0, 0, 0);
            {
                bf16x8 b4 = *(const bf16x8*)&WS[8192 + (nt * 64 + lane) * 8];
                a = __builtin_amdgcn_mfma_f32_16x16x32_bf16(aA4, b4, a, 0, 0, 0);
            }
            #pragma unroll
            for (int rr = 0; rr < 4; ++rr)
                S[0][w][quad * 4 + rr][nt * 16 + l15] = bfb(silu_f(a[rr] + b1v[nt]));
        }
        #pragma unroll
        for (int nt = 0; nt < 4; ++nt) {
            f32x4 a = {0.f, 0.f, 0.f, 0.f};
            a = __builtin_amdgcn_mfma_f32_16x16x32_bf16(aB0, w1f[0][nt], a, 0, 0, 0);
            a = __builtin_amdgcn_mfma_f32_16x16x32_bf16(aB1, w1f[1][nt], a, 0, 0, 0);
            a = __builtin_amdgcn_mfma_f32_16x16x32_bf16(aB2, w1f[2][nt], a, 0, 0, 0);
            a = __builtin_amdgcn_mfma_f32_16x16x32_bf16(aB3, w1f[3][nt], a, 0, 0, 0);
            {
                bf16x8 b4 = *(const bf16x8*)&WS[8192 + (nt * 64 + lane) * 8];
                a = __builtin_amdgcn_mfma_f32_16x16x32_bf16(aB4, b4, a, 0, 0, 0);
            }
            #pragma unroll
            for (int rr = 0; rr < 4; ++rr)
                S[1][w][quad * 4 + rr][nt * 16 + l15] = bfb(silu_f(a[rr] + b1v[nt]));
        }
        WFENCE();

        // ---- GEMM2 (A,B): H1 @ W2 -> msg (alias back into cols 0..63) ----
        bf16x8 a2A[2], a2B[2];
        #pragma unroll
        for (int s = 0; s < 2; ++s) {
            a2A[s] = *(const bf16x8*)&S[0][w][l15][s * 32 + quad * 8];
            a2B[s] = *(const bf16x8*)&S[1][w][l15][s * 32 + quad * 8];
        }
        WFENCE();   // a2 in regs before msg overwrites
        #pragma unroll
        for (int nt = 0; nt < 4; ++nt) {
            f32x4 m = {0.f, 0.f, 0.f, 0.f};
            #pragma unroll
            for (int s = 0; s < 2; ++s) {
                bf16x8 bf = *(const bf16x8*)&WS[((s * 4 + nt) * 64 + lane) * 8];
                m = __builtin_amdgcn_mfma_f32_16x16x32_bf16(a2A[s], bf, m, 0, 0, 0);
            }
            #pragma unroll
            for (int rr = 0; rr < 4; ++rr)
                S[0][w][quad * 4 + rr][nt * 16 + l15] = bfb(silu_f(m[rr] + b2v[nt]));
        }
        #pragma unroll
        for (int nt = 0; nt < 4; ++nt) {
            f32x4 m = {0.f, 0.f, 0.f, 0.f};
            #pragma unroll
            for (int s = 0; s < 2; ++s) {
                bf16x8 bf = *(const bf16x8*)&WS[((s * 4 + nt) * 64 + lane) * 8];
                m = __builtin_amdgcn_mfma_f32_16x16x32_bf16(a2B[s], bf, m, 0, 0, 0);
            }
            #pragma unroll
            for (int rr = 0; rr < 4; ++rr)
                S[1][w][quad * 4 + rr][nt * 16 + l15] = bfb(silu_f(m[rr] + b2v[nt]));
        }
        WFENCE();

        // ---- GEMM3 (A,B): msg @ cW1 -> c1; dot cW2 -> cm (S col 64 f32) ----
        bf16x8 a3A[2], a3B[2];
        #pragma unroll
        for (int s = 0; s < 2; ++s) {
            a3A[s] = *(const bf16x8*)&S[0][w][l15][s * 32 + quad * 8];
            a3B[s] = *(const bf16x8*)&S[1][w][l15][s * 32 + quad * 8];
        }
        float prA[4] = {0.f, 0.f, 0.f, 0.f};
        float prB[4] = {0.f, 0.f, 0.f, 0.f};
        #pragma unroll
        for (int nt = 0; nt < 4; ++nt) {
            f32x4 qA = {0.f, 0.f, 0.f, 0.f};
            f32x4 qB = {0.f, 0.f, 0.f, 0.f};
            #pragma unroll
            for (int s = 0; s < 2; ++s) {
                bf16x8 bf = *(const bf16x8*)&WS[4096 + ((s * 4 + nt) * 64 + lane) * 8];
                qA = __builtin_amdgcn_mfma_f32_16x16x32_bf16(a3A[s], bf, qA, 0, 0, 0);
                qB = __builtin_amdgcn_mfma_f32_16x16x32_bf16(a3B[s], bf, qB, 0, 0, 0);
            }
            #pragma unroll
            for (int rr = 0; rr < 4; ++rr) {
                prA[rr] += silu_f(qA[rr] + cb1v[nt]) * cw2v[nt];
                prB[rr] += silu_f(qB[rr] + cb1v[nt]) * cw2v[nt];
            }
        }
        #pragma unroll
        for (int rr = 0; rr < 4; ++rr) {
            float tA = prA[rr], tB = prB[rr];
            tA += __shfl_xor(tA, 1, 64);
            tB += __shfl_xor(tB, 1, 64);
            tA += __shfl_xor(tA, 2, 64);
            tB += __shfl_xor(tB, 2, 64);
            tA += __shfl_xor(tA, 4, 64);
            tB += __shfl_xor(tB, 4, 64);
            tA += __shfl_xor(tA, 8, 64);
            tB += __shfl_xor(tB, 8, 64);
            if (l15 == 0) {
                *(float*)&S[0][w][quad * 4 + rr][64] = tA + cb2s;
                *(float*)&S[1][w][quad * 4 + rr][64] = tB + cb2s;
            }
        }
        WFENCE();

        // ---- segmented flush (A, then B if real): rows sorted by RI ----
        #pragma unroll
        for (int tb = 0; tb < 2; ++tb) {
            if (tb == 1 && !haveB) break;
            if (lane < 32) {   // msg -> tmsgb: lane owns cols {2l,2l+1}, pk atomic
                unsigned both = *(const unsigned*)&S[tb][w][0][2 * lane];
                float ax = b2f((unsigned short)(both & 0xffffu));
                float ay = b2f((unsigned short)(both >> 16));
                int cur_r = RI[tb][w][0];
                #pragma unroll
                for (int g = 1; g < 16; ++g) {
                    const int ri = RI[tb][w][g];
                    unsigned bv = *(const unsigned*)&S[tb][w][g][2 * lane];
                    const float vx = b2f((unsigned short)(bv & 0xffffu));
                    const float vy = b2f((unsigned short)(bv >> 16));
                    if (ri != cur_r) {
                        atomic_pk_bf16(&tmsgb[(size_t)cur_r * HH + 2 * lane], pk2(ax, ay));
                        ax = 0.f; ay = 0.f; cur_r = ri;
                    }
                    ax += vx; ay += vy;
                }
                atomic_pk_bf16(&tmsgb[(size_t)cur_r * HH + 2 * lane], pk2(ax, ay));
            } else if ((lane & 31) < 3) {   // f = rij*cm -> sum_f (fp32, tiny)
                const int sl = lane & 31;
                float acc = RV[tb][w][0][sl] * (*(const float*)&S[tb][w][0][64]);
                int cur_r = RI[tb][w][0];
                #pragma unroll
                for (int g = 1; g < 16; ++g) {
                    const int ri = RI[tb][w][g];
                    const float v = RV[tb][w][g][sl] * (*(const float*)&S[tb][w][g][64]);
                    if (ri != cur_r) {
                        atomicAdd(&sum_f[3 * cur_r + sl], acc);
                        acc = 0.f; cur_r = ri;
                    }
                    acc += v;
                }
                atomicAdd(&sum_f[3 * cur_r + sl], acc);
            }
        }
        WFENCE();   // flush reads drained before next iter's S writes (WAR)
    }
}

// ---------------- MFMA node kernel: 16 nodes per wave ----------------
// Reads bf16 tmsgb directly; zeroes tmsgb/sum_f after use (next layer's init).
// Updates both xo (output) and x4 (padded mirror for next layer's edge pass).
__global__ __launch_bounds__(256) void node_mfma_kernel(
    float* __restrict__ x, float* __restrict__ x4, float* __restrict__ h,
    unsigned short* __restrict__ hb,
    float* __restrict__ sum_f, const int* __restrict__ deg,
    unsigned short* __restrict__ tmsgb,
    const unsigned short* __restrict__ nw1b, const unsigned short* __restrict__ nw2b,
    const float* __restrict__ nb1, const float* __restrict__ nb2)
{
    __shared__ __align__(16) unsigned short S[4][16][136];
    const int tid = threadIdx.x;
    const int w = tid >> 6, lane = tid & 63;
    const int l15 = lane & 15, quad = lane >> 4;
    const int le = lane >> 2, sub = lane & 3;
    const int t = blockIdx.x * 4 + w;
    if (t >= NN / 16) return;                      // 3125 waves exactly

    // gather (fully coalesced): [hb | tmsgb] -> S[16][128]; zero tmsgb after
    {
        unsigned short* Srow = &S[w][le][0];
        const int n = t * 16 + le;
        const unsigned short* hr = hb + (size_t)n * HH + sub * 16;
        *(uint4*)&Srow[sub * 16]     = *(const uint4*)(hr);
        *(uint4*)&Srow[sub * 16 + 8] = *(const uint4*)(hr + 8);
        unsigned short* tm = tmsgb + (size_t)n * HH + sub * 16;
        *(uint4*)&Srow[64 + sub * 16]     = *(const uint4*)(tm);
        *(uint4*)&Srow[64 + sub * 16 + 8] = *(const uint4*)(tm + 8);
        const uint4 z = {0u, 0u, 0u, 0u};
        *(uint4*)(tm)     = z;
        *(uint4*)(tm + 8) = z;
    }
    // x update: one lane per node; zero sum_f after
    if (lane < 16) {
        const int nn = t * 16 + lane;
        const float cn = fmaxf((float)deg[nn], 1.0f);
        const float rc = __builtin_amdgcn_rcpf(cn);
        #pragma unroll
        for (int d3 = 0; d3 < 3; ++d3) {
            float tf = sum_f[3 * nn + d3] * rc;
            tf = fminf(fmaxf(tf, -100.0f), 100.0f);
            x[3 * nn + d3] += tf;
            x4[4 * nn + d3] += tf;
            sum_f[3 * nn + d3] = 0.0f;
        }
    }
    WFENCE();

    // GEMM1: [16x128] @ nW1[128x64] -> SiLU -> alias cols 0..63
    bf16x8 af[4];
    #pragma unroll
    for (int s = 0; s < 4; ++s)
        af[s] = *(const bf16x8*)&S[w][l15][s * 32 + quad * 8];
    WFENCE();
    float nb1v[4], nb2v[4];
    #pragma unroll
    for (int nt = 0; nt < 4; ++nt) {
        nb1v[nt] = nb1[nt * 16 + l15];
        nb2v[nt] = nb2[nt * 16 + l15];
    }
    #pragma unroll
    for (int nt = 0; nt < 4; ++nt) {
        f32x4 a = {0.f, 0.f, 0.f, 0.f};
        #pragma unroll
        for (int s = 0; s < 4; ++s) {
            bf16x8 bf = *(const bf16x8*)(nw1b + ((s * 4 + nt) * 64 + lane) * 8);
            a = __builtin_amdgcn_mfma_f32_16x16x32_bf16(af[s], bf, a, 0, 0, 0);
        }
        #pragma unroll
        for (int rr = 0; rr < 4; ++rr)
            S[w][quad * 4 + rr][nt * 16 + l15] = bfb(silu_f(a[rr] + nb1v[nt]));
    }
    WFENCE();

    // GEMM2: [16x64] @ nW2[64x64] -> h (no act)
    bf16x8 a2[2];
    #pragma unroll
    for (int s = 0; s < 2; ++s)
        a2[s] = *(const bf16x8*)&S[w][l15][s * 32 + quad * 8];
    #pragma unroll
    for (int nt = 0; nt < 4; ++nt) {
        f32x4 m = {0.f, 0.f, 0.f, 0.f};
        #pragma unroll
        for (int s = 0; s < 2; ++s) {
            bf16x8 bf = *(const bf16x8*)(nw2b + ((s * 4 + nt) * 64 + lane) * 8);
            m = __builtin_amdgcn_mfma_f32_16x16x32_bf16(a2[s], bf, m, 0, 0, 0);
        }
        #pragma unroll
        for (int rr = 0; rr < 4; ++rr) {
            const float v = m[rr] + nb2v[nt];
            const size_t nd = (size_t)(t * 16 + quad * 4 + rr) * HH + nt * 16 + l15;
            h[nd] = v;
            hb[nd] = bfb(v);
        }
    }
}

extern "C" void kernel_launch(void* const* d_in, const int* in_sizes, int n_in,
                              void* d_out, int out_size, void* d_ws, size_t ws_size,
                              hipStream_t stream) {
    const float* x_in  = (const float*)d_in[0];
    const float* h_in  = (const float*)d_in[1];
    const int*   row   = (const int*)d_in[2];
    const int*   col   = (const int*)d_in[3];
    const float* efea  = (const float*)d_in[4];
    const float* emb_W = (const float*)d_in[5];
    const float* emb_b = (const float*)d_in[6];
    const float* eW1   = (const float*)d_in[7];
    const float* eb1   = (const float*)d_in[8];
    const float* eW2   = (const float*)d_in[9];
    const float* eb2   = (const float*)d_in[10];
    const float* cW1   = (const float*)d_in[11];
    const float* cb1   = (const float*)d_in[12];
    const float* cW2   = (const float*)d_in[13];
    const float* cb2   = (const float*)d_in[14];
    const float* nW1   = (const float*)d_in[15];
    const float* nb1   = (const float*)d_in[16];
    const float* nW2   = (const float*)d_in[17];
    const float* nb2   = (const float*)d_in[18];

    float* out = (float*)d_out;
    float* xo = out;                 // N*3
    float* ho = out + NN * 3;        // N*64

    // workspace layout (16B-aligned segments)
    char* wsb = (char*)d_ws;
    float* sum_f = (float*)wsb;                                  //    600,000 B
    unsigned short* tmsgb = (unsigned short*)(wsb + 600000);     //  6,400,000 B
    unsigned short* efs = (unsigned short*)(wsb + 7000000);      // 12,800,000 B
    unsigned short* hb  = (unsigned short*)(wsb + 19800000);     //  6,400,000 B
    unsigned short* wsW = (unsigned short*)(wsb + 26200000);     //    122,880 B
    int* deg    = (int*)(wsb + 26322880);                        //    200,000 B
    int* cur    = (int*)(wsb + 26522880);                        //    200,000 B
    int2* rc    = (int2*)(wsb + 26722880);                       //  6,400,000 B
    float* x4   = (float*)(wsb + 33122880);                      //    800,000 B
    int* bsum   = (int*)(wsb + 33922880);                        //        800 B
    int* boff   = (int*)(wsb + 33923680);                        //        800 B

    // zero deg, then fused setup (hist + swizzle + embed + zero + x copies)
    hipMemsetAsync(deg, 0, 200000, stream);
    setup_kernel<<<17917, 256, 0, stream>>>(
        row, deg,
        eW1, eW2, cW1, nW1, nW2, wsW,
        h_in, emb_W, emb_b, ho, hb,
        wsb, x_in, xo, x4);
    // row scan + counting sort
    scanA_kernel<<<200, 256, 0, stream>>>(deg, bsum);
    scanB_kernel<<<1, 256, 0, stream>>>(bsum, boff);
    scanC_kernel<<<200, 256, 0, stream>>>(deg, boff, cur);
    fill_kernel<<<MM / 256, 256, 0, stream>>>(row, col, efea, cur, rc, efs);

    for (int i = 0; i < 2; ++i) {
        const unsigned short* L = wsW + i * 30720;
        edge_mfma_kernel<<<NB_EDGE, 256, 0, stream>>>(
            x4, hb, rc, efs,
            L, L + 10240, L + 14336,
            eb1 + i * 64, eb2 + i * 64, cb1 + i * 64, cW2 + i * 64, cb2 + i,
            sum_f, tmsgb);
        node_mfma_kernel<<<(NN / 16 + 3) / 4, 256, 0, stream>>>(
            xo, x4, ho, hb, sum_f, deg, tmsgb,
            L + 18432, L + 26624, nb1 + i * 64, nb2 + i * 64);
    }
}

// Round 6
// 424.129 us; speedup vs baseline: 1.3357x; 1.0054x over previous
//
#include <hip/hip_runtime.h>
#include <math.h>

#define NN 50000
#define MM 800000
#define HH 64
#define NB_EDGE 1792
#define NTILE 12500                 // MM / 64 edges per block-tile

typedef short bf16x8 __attribute__((ext_vector_type(8)));
typedef float f32x4  __attribute__((ext_vector_type(4)));

// per-wave LDS fence: all LDS regions are wave-private; lockstep + lgkmcnt
// drain replaces __syncthreads
#define WFENCE() asm volatile("s_waitcnt lgkmcnt(0)" ::: "memory")

__device__ __forceinline__ float silu_f(float v) {
    return v * __builtin_amdgcn_rcpf(1.0f + __expf(-v));
}
// round-half-up fp32 -> bf16 bits (0.5 ulp max)
__device__ __forceinline__ unsigned short bfb(float a) {
    return (unsigned short)((__float_as_uint(a) + 0x8000u) >> 16);
}
// pack two f32 -> one u32 of 2 bf16 (low = lo, high = hi), single VALU op
__device__ __forceinline__ unsigned cvtpk(float lo, float hi) {
    unsigned r;
    asm("v_cvt_pk_bf16_f32 %0, %1, %2" : "=v"(r) : "v"(lo), "v"(hi));
    return r;
}
// pack two f32 -> bf16x2 via v_perm (low = a, high = b)
__device__ __forceinline__ unsigned pk2(float a, float b) {
    return __builtin_amdgcn_perm(__float_as_uint(b) + 0x8000u,
                                 __float_as_uint(a) + 0x8000u, 0x07060302u);
}
__device__ __forceinline__ float b2f(unsigned short s) {
    return __uint_as_float((unsigned)s << 16);
}
// packed bf16x2 atomic add
__device__ __forceinline__ void atomic_pk_bf16(unsigned short* addr, unsigned pk) {
    asm volatile("global_atomic_pk_add_bf16 %0, %1, off"
                 :: "v"((unsigned long long)(size_t)addr), "v"(pk) : "memory");
}

// ---------------- fused setup ----------------
// blocks [0,3125): deg histogram
// blocks [3125,3365): weight pre-swizzle (per layer 30720 shorts)
// blocks [3365,15865): embedding
// blocks [15865,17574): zero sum_f+tmsgb (7,000,000 B)
// blocks [17574,17721): copy x_in -> xo (uint4)
// blocks [17721,17917): build padded x4 mirror
__global__ __launch_bounds__(256) void setup_kernel(
    const int* __restrict__ row, int* __restrict__ deg,
    const float* __restrict__ eW1, const float* __restrict__ eW2,
    const float* __restrict__ cW1, const float* __restrict__ nW1,
    const float* __restrict__ nW2, unsigned short* __restrict__ wsW,
    const float* __restrict__ h_in, const float* __restrict__ emb_W,
    const float* __restrict__ emb_b, float* __restrict__ h_out,
    unsigned short* __restrict__ hb,
    char* __restrict__ zbase, const float* __restrict__ x_in,
    float* __restrict__ xo, float* __restrict__ x4)
{
    const int b = blockIdx.x;
    if (b < 3125) {
        const int e = b * 256 + threadIdx.x;
        atomicAdd(&deg[row[e]], 1);
    } else if (b < 3365) {
        const int i = (b - 3125) * 256 + threadIdx.x;     // 0 .. 61439
        const int layer = i / 30720;
        const int rem = i - layer * 30720;
        float val;
        if (rem < 10240) {
            const int j = rem & 7, lane = (rem >> 3) & 63, nt = (rem >> 9) & 3, s = rem >> 11;
            const int kp = s * 32 + ((lane >> 4) << 3) + j;
            const int n  = nt * 16 + (lane & 15);
            if (kp > 136) val = 0.0f;
            else {
                const int k = (kp == 136) ? 0 : kp + 1;   // k'=136 is the r2 row
                val = eW1[layer * 137 * 64 + k * 64 + n];
            }
        } else if (rem < 14336) {
            const int r2 = rem - 10240;
            const int j = r2 & 7, lane = (r2 >> 3) & 63, nt = (r2 >> 9) & 3, s = r2 >> 11;
            val = eW2[layer * 4096 + (s * 32 + ((lane >> 4) << 3) + j) * 64 + nt * 16 + (lane & 15)];
        } else if (rem < 18432) {
            const int r3 = rem - 14336;
            const int j = r3 & 7, lane = (r3 >> 3) & 63, nt = (r3 >> 9) & 3, s = r3 >> 11;
            val = cW1[layer * 4096 + (s * 32 + ((lane >> 4) << 3) + j) * 64 + nt * 16 + (lane & 15)];
        } else if (rem < 26624) {
            const int r4 = rem - 18432;
            const int j = r4 & 7, lane = (r4 >> 3) & 63, nt = (r4 >> 9) & 3, s = r4 >> 11;
            const int kp = s * 32 + ((lane >> 4) << 3) + j;      // < 128
            val = nW1[layer * 8192 + kp * 64 + nt * 16 + (lane & 15)];
        } else {
            const int r5 = rem - 26624;
            const int j = r5 & 7, lane = (r5 >> 3) & 63, nt = (r5 >> 9) & 3, s = r5 >> 11;
            val = nW2[layer * 4096 + (s * 32 + ((lane >> 4) << 3) + j) * 64 + nt * 16 + (lane & 15)];
        }
        wsW[i] = bfb(val);
    } else if (b < 15865) {
        const int idx = (b - 3365) * 256 + threadIdx.x;   // over N*64
        const int n = idx >> 6, j = idx & 63;
        float acc = emb_b[j];
        #pragma unroll
        for (int k = 0; k < 16; ++k)
            acc += h_in[n * 16 + k] * emb_W[k * HH + j];
        h_out[idx] = acc;
        hb[idx] = bfb(acc);
    } else if (b < 17574) {
        const int t = (b - 15865) * 256 + threadIdx.x;
        if (t < 437500) {                                  // 7,000,000 / 16
            const uint4 z = {0u, 0u, 0u, 0u};
            *(uint4*)(zbase + (size_t)t * 16) = z;
        }
    } else if (b < 17721) {
        const int t = (b - 17574) * 256 + threadIdx.x;
        if (t < 37500)                                     // N*3 floats / 4
            ((uint4*)xo)[t] = ((const uint4*)x_in)[t];
    } else {
        const int n = (b - 17721) * 256 + threadIdx.x;
        if (n < NN) {
            float4 v;
            v.x = x_in[3 * n + 0];
            v.y = x_in[3 * n + 1];
            v.z = x_in[3 * n + 2];
            v.w = 0.0f;
            ((float4*)x4)[n] = v;
        }
    }
}

// parallel scan over NN, phase A: 200 blocks x 250-node chunks -> blocksum
__global__ __launch_bounds__(256) void scanA_kernel(const int* __restrict__ deg,
                                                    int* __restrict__ bsum) {
    __shared__ int ps[256];
    const int t = threadIdx.x;
    const int base = blockIdx.x * 250;
    int v = (t < 250) ? deg[base + t] : 0;
    ps[t] = v;
    __syncthreads();
    for (int off = 1; off < 256; off <<= 1) {
        const int u = (t >= off) ? ps[t - off] : 0;
        __syncthreads();
        ps[t] += u;
        __syncthreads();
    }
    if (t == 255) bsum[blockIdx.x] = ps[255];
}

// phase B: exclusive scan of 200 blocksums (single small block)
__global__ __launch_bounds__(256) void scanB_kernel(const int* __restrict__ bsum,
                                                    int* __restrict__ boff) {
    __shared__ int ps[256];
    const int t = threadIdx.x;
    int v = (t < 200) ? bsum[t] : 0;
    ps[t] = v;
    __syncthreads();
    for (int off = 1; off < 256; off <<= 1) {
        const int u = (t >= off) ? ps[t - off] : 0;
        __syncthreads();
        ps[t] += u;
        __syncthreads();
    }
    if (t < 200) boff[t] = ps[t] - v;     // exclusive
}

// phase C: per-chunk exclusive scan + global offset -> cur
__global__ __launch_bounds__(256) void scanC_kernel(const int* __restrict__ deg,
                                                    const int* __restrict__ boff,
                                                    int* __restrict__ cur) {
    __shared__ int ps[256];
    const int t = threadIdx.x;
    const int base = blockIdx.x * 250;
    int v = (t < 250) ? deg[base + t] : 0;
    ps[t] = v;
    __syncthreads();
    for (int off = 1; off < 256; off <<= 1) {
        const int u = (t >= off) ? ps[t - off] : 0;
        __syncthreads();
        ps[t] += u;
        __syncthreads();
    }
    if (t < 250)
        cur[base + t] = boff[blockIdx.x] + ps[t] - v;   // exclusive prefix
}

// one-pass counting-sort fill: rc (int2 interleaved) + efs in row-sorted order
__global__ __launch_bounds__(256) void fill_kernel(
    const int* __restrict__ row, const int* __restrict__ col,
    const float* __restrict__ efea, int* __restrict__ cur,
    int2* __restrict__ rc, unsigned short* __restrict__ efs)
{
    const int e = blockIdx.x * 256 + threadIdx.x;
    const int r = row[e];
    const int pos = atomicAdd(&cur[r], 1);
    int2 v; v.x = r; v.y = col[e];
    rc[pos] = v;                                       // one 8B scatter
    const float4* ef = (const float4*)(efea + (size_t)e * 8);
    const float4 e0 = ef[0], e1 = ef[1];
    uint4 ue = { pk2(e0.x, e0.y), pk2(e0.z, e0.w), pk2(e1.x, e1.y), pk2(e1.z, e1.w) };
    *(uint4*)(efs + (size_t)pos * 8) = ue;
}

// ---------------- MFMA edge kernel: 16 sorted edges per wave, swapped ops ---
// All MFMAs use SWAPPED operands: mfma(weight_frag, data_frag) — valid because
// A- and B-fragment layouts of 16x16x32 are identical (16-dim on l15, K on
// quad*8+j), so the existing swizzle serves both. Output: lane (l15,quad)
// holds D[e=l15][n=nt*16+quad*4+rr] — each lane owns 16 columns of ITS edge.
// Wins vs unswapped: pairwise cvt_pk epilogues (8 ops + 4 ds_write_b64 vs 32
// ops + 16 ds_write_b16), lane-local GEMM3 dot (2 shfl vs 32-op butterfly),
// and biases folded into MFMA via a ones-fragment K-slice (0 VALU, 0 VGPR):
// GEMM1 bias rides the free kp=137 pad slot of W1 slice 4; GEMM2/3 get one
// extra bias-row MFMA each. Direct global->register gather as in R4.
__global__ __launch_bounds__(256, 4) void edge_mfma_kernel(
    const float* __restrict__ x4, const unsigned short* __restrict__ hb,
    const int2* __restrict__ rc, const unsigned short* __restrict__ efs,
    const unsigned short* __restrict__ w1b, const unsigned short* __restrict__ w2b,
    const unsigned short* __restrict__ cw1b,
    const float* __restrict__ b1, const float* __restrict__ b2,
    const float* __restrict__ cb1, const float* __restrict__ cw2,
    const float* __restrict__ cb2,
    float* __restrict__ sum_f, unsigned short* __restrict__ tmsgb)
{
    __shared__ __align__(16) unsigned short S[4][16][80];  // [0,64)=H1/msg, [64,66)=cm f32
    __shared__ float RV[4][16][4];
    __shared__ int   RI[4][16];
    __shared__ __align__(16) unsigned short WS[14336];
    // WS shorts: [0,4096)=w2 s0,s1   [4096,6144)=w2 bias slice
    //            [6144,10240)=cw1 s0,s1  [10240,12288)=cw1 bias slice
    //            [12288,14336)=w1 slice4 (kp137 patched with b1)

    const int tid = threadIdx.x;
    const int w = tid >> 6, lane = tid & 63;
    const int l15 = lane & 15, quad = lane >> 4;

    // stage weights + bias slices into LDS, block-shared
    {
        const uint4* s2 = (const uint4*)w2b;
        const uint4* s3 = (const uint4*)cw1b;
        const uint4* s4 = (const uint4*)w1b;   // slice4 = uint4 idx [1024,1280)
        uint4* dst = (uint4*)WS;
        dst[tid]        = s2[tid];
        dst[256 + tid]  = s2[256 + tid];
        dst[768 + tid]  = s3[tid];
        dst[1024 + tid] = s3[256 + tid];
        const int ln = tid & 63, ntb = tid >> 6;
        uint4 z4 = s4[1024 + tid];
        if ((ln >> 4) == 1)    // quad==1, j==1 slot = kp137 (high half of .x)
            z4.x = (z4.x & 0x0000FFFFu) | ((unsigned)bfb(b1[ntb * 16 + (ln & 15)]) << 16);
        dst[1536 + tid] = z4;
        uint4 zb = {0u, 0u, 0u, 0u};
        if ((ln >> 4) == 0) zb.x = (unsigned)bfb(b2[ntb * 16 + (ln & 15)]);
        dst[512 + tid] = zb;
        uint4 zc = {0u, 0u, 0u, 0u};
        if ((ln >> 4) == 0) zc.x = (unsigned)bfb(cb1[ntb * 16 + (ln & 15)]);
        dst[1280 + tid] = zc;
    }

    // hoist W1 slices 0..3 into registers (loop-invariant; AGPR-parked, 64)
    bf16x8 w1f[4][4];
    #pragma unroll
    for (int s = 0; s < 4; ++s)
        #pragma unroll
        for (int nt = 0; nt < 4; ++nt)
            w1f[s][nt] = *(const bf16x8*)(w1b + ((s * 4 + nt) * 64 + lane) * 8);

    // cw2 dot weights on the (nt,rr) axis now: float4 per nt
    float4 cw2q[4];
    #pragma unroll
    for (int nt = 0; nt < 4; ++nt)
        cw2q[nt] = *(const float4*)(cw2 + nt * 16 + quad * 4);
    const float cb2s = cb2[0];

    // ones B-fragment: B[k=0][e]=1 for all e (bias K-slice driver)
    bf16x8 onef = {0, 0, 0, 0, 0, 0, 0, 0};
    if (quad == 0) onef[0] = (short)0x3F80;

    __syncthreads();   // WS visible to all 4 waves

    for (int bt = blockIdx.x; bt < NTILE; bt += NB_EDGE) {
        const int t = bt * 4 + w;
        const int p = t * 16 + l15;          // this lane's edge (shared by 4 quads)
        const int2 rcv = rc[p];
        const int r = rcv.x, c = rcv.y;

        // ---- direct B-fragment gather (data): X[e=l15][k=quad*8+j] ----
        const unsigned short* hr = hb + (size_t)r * HH + quad * 8;
        const unsigned short* hc = hb + (size_t)c * HH + quad * 8;
        bf16x8 af0 = *(const bf16x8*)(hr);
        bf16x8 af1 = *(const bf16x8*)(hr + 32);
        bf16x8 af2 = *(const bf16x8*)(hc);
        bf16x8 af3 = *(const bf16x8*)(hc + 32);
        bf16x8 af4 = {0, 0, 0, 0, 0, 0, 0, 0};
        if (quad == 0) {
            af4 = *(const bf16x8*)(efs + (size_t)p * 8);
            RI[w][l15] = r;
        } else if (quad == 1) {
            const float4 xr = ((const float4*)x4)[r];
            const float4 xc = ((const float4*)x4)[c];
            const float rx = xr.x - xc.x;
            const float ry = xr.y - xc.y;
            const float rz = xr.z - xc.z;
            RV[w][l15][0] = rx; RV[w][l15][1] = ry; RV[w][l15][2] = rz;
            af4[0] = (short)bfb(rx * rx + ry * ry + rz * rz);
            af4[1] = (short)0x3F80;   // kp=137 constant-1 -> b1 bias row
        }

        // ---- GEMM1 swapped: D[n][e] = W1^T · X^T; lane holds H1[l15][nt*16+q*4+rr]
        #pragma unroll
        for (int nt = 0; nt < 4; ++nt) {
            f32x4 a = {0.f, 0.f, 0.f, 0.f};
            a = __builtin_amdgcn_mfma_f32_16x16x32_bf16(w1f[0][nt], af0, a, 0, 0, 0);
            a = __builtin_amdgcn_mfma_f32_16x16x32_bf16(w1f[1][nt], af1, a, 0, 0, 0);
            a = __builtin_amdgcn_mfma_f32_16x16x32_bf16(w1f[2][nt], af2, a, 0, 0, 0);
            a = __builtin_amdgcn_mfma_f32_16x16x32_bf16(w1f[3][nt], af3, a, 0, 0, 0);
            {
                bf16x8 b4 = *(const bf16x8*)&WS[12288 + (nt * 64 + lane) * 8];
                a = __builtin_amdgcn_mfma_f32_16x16x32_bf16(b4, af4, a, 0, 0, 0);
            }
            uint2 pkv;
            pkv.x = cvtpk(silu_f(a[0]), silu_f(a[1]));
            pkv.y = cvtpk(silu_f(a[2]), silu_f(a[3]));
            *(uint2*)&S[w][l15][nt * 16 + quad * 4] = pkv;   // row=e, cols n..n+3
        }
        WFENCE();

        // ---- GEMM2 swapped: B-frags = H1[l15][s*32+quad*8..] from S ----
        bf16x8 h1f0 = *(const bf16x8*)&S[w][l15][quad * 8];
        bf16x8 h1f1 = *(const bf16x8*)&S[w][l15][32 + quad * 8];
        WFENCE();   // frags in regs before msg overwrites
        #pragma unroll
        for (int nt = 0; nt < 4; ++nt) {
            f32x4 m = {0.f, 0.f, 0.f, 0.f};
            {
                bf16x8 wf = *(const bf16x8*)&WS[((0 * 4 + nt) * 64 + lane) * 8];
                m = __builtin_amdgcn_mfma_f32_16x16x32_bf16(wf, h1f0, m, 0, 0, 0);
            }
            {
                bf16x8 wf = *(const bf16x8*)&WS[((1 * 4 + nt) * 64 + lane) * 8];
                m = __builtin_amdgcn_mfma_f32_16x16x32_bf16(wf, h1f1, m, 0, 0, 0);
            }
            {
                bf16x8 wb = *(const bf16x8*)&WS[4096 + (nt * 64 + lane) * 8];
                m = __builtin_amdgcn_mfma_f32_16x16x32_bf16(wb, onef, m, 0, 0, 0);
            }
            uint2 pkv;
            pkv.x = cvtpk(silu_f(m[0]), silu_f(m[1]));
            pkv.y = cvtpk(silu_f(m[2]), silu_f(m[3]));
            *(uint2*)&S[w][l15][nt * 16 + quad * 4] = pkv;   // msg[e][n]
        }
        WFENCE();

        // ---- GEMM3 swapped: c1[l15][n]; lane-local dot with cw2 ----
        bf16x8 mf0 = *(const bf16x8*)&S[w][l15][quad * 8];
        bf16x8 mf1 = *(const bf16x8*)&S[w][l15][32 + quad * 8];
        float pr = 0.f;
        #pragma unroll
        for (int nt = 0; nt < 4; ++nt) {
            f32x4 q3 = {0.f, 0.f, 0.f, 0.f};
            {
                bf16x8 wf = *(const bf16x8*)&WS[6144 + ((0 * 4 + nt) * 64 + lane) * 8];
                q3 = __builtin_amdgcn_mfma_f32_16x16x32_bf16(wf, mf0, q3, 0, 0, 0);
            }
            {
                bf16x8 wf = *(const bf16x8*)&WS[6144 + ((1 * 4 + nt) * 64 + lane) * 8];
                q3 = __builtin_amdgcn_mfma_f32_16x16x32_bf16(wf, mf1, q3, 0, 0, 0);
            }
            {
                bf16x8 wb = *(const bf16x8*)&WS[10240 + (nt * 64 + lane) * 8];
                q3 = __builtin_amdgcn_mfma_f32_16x16x32_bf16(wb, onef, q3, 0, 0, 0);
            }
            pr += silu_f(q3[0]) * cw2q[nt].x;
            pr += silu_f(q3[1]) * cw2q[nt].y;
            pr += silu_f(q3[2]) * cw2q[nt].z;
            pr += silu_f(q3[3]) * cw2q[nt].w;
        }
        pr += __shfl_xor(pr, 16, 64);    // reduce over the 4 quads of edge l15
        pr += __shfl_xor(pr, 32, 64);
        if (quad == 0) *(float*)&S[w][l15][64] = pr + cb2s;
        WFENCE();

        // ---- segmented flush: rows sorted by RI within the tile ----
        if (lane < 32) {   // msg -> tmsgb: lane owns cols {2l, 2l+1}, pk atomic
            unsigned both = *(const unsigned*)&S[w][0][2 * lane];
            float ax = b2f((unsigned short)(both & 0xffffu));
            float ay = b2f((unsigned short)(both >> 16));
            int cur_r = RI[w][0];
            #pragma unroll
            for (int g = 1; g < 16; ++g) {
                const int ri = RI[w][g];
                unsigned bv = *(const unsigned*)&S[w][g][2 * lane];
                const float vx = b2f((unsigned short)(bv & 0xffffu));
                const float vy = b2f((unsigned short)(bv >> 16));
                if (ri != cur_r) {
                    atomic_pk_bf16(&tmsgb[(size_t)cur_r * HH + 2 * lane], pk2(ax, ay));
                    ax = 0.f; ay = 0.f; cur_r = ri;
                }
                ax += vx; ay += vy;
            }
            atomic_pk_bf16(&tmsgb[(size_t)cur_r * HH + 2 * lane], pk2(ax, ay));
        } else if ((lane & 31) < 3) {   // f = rij*cm -> sum_f (fp32, tiny)
            const int sl = lane & 31;
            float acc = RV[w][0][sl] * (*(const float*)&S[w][0][64]);
            int cur_r = RI[w][0];
            #pragma unroll
            for (int g = 1; g < 16; ++g) {
                const int ri = RI[w][g];
                const float v = RV[w][g][sl] * (*(const float*)&S[w][g][64]);
                if (ri != cur_r) {
                    atomicAdd(&sum_f[3 * cur_r + sl], acc);
                    acc = 0.f; cur_r = ri;
                }
                acc += v;
            }
            atomicAdd(&sum_f[3 * cur_r + sl], acc);
        }
        WFENCE();   // flush reads drained before next iter's S writes (WAR)
    }
}

// ---------------- MFMA node kernel: 16 nodes per wave ----------------
// Reads bf16 tmsgb directly; zeroes tmsgb/sum_f after use (next layer's init).
// Updates both xo (output) and x4 (padded mirror for next layer's edge pass).
__global__ __launch_bounds__(256) void node_mfma_kernel(
    float* __restrict__ x, float* __restrict__ x4, float* __restrict__ h,
    unsigned short* __restrict__ hb,
    float* __restrict__ sum_f, const int* __restrict__ deg,
    unsigned short* __restrict__ tmsgb,
    const unsigned short* __restrict__ nw1b, const unsigned short* __restrict__ nw2b,
    const float* __restrict__ nb1, const float* __restrict__ nb2)
{
    __shared__ __align__(16) unsigned short S[4][16][136];
    const int tid = threadIdx.x;
    const int w = tid >> 6, lane = tid & 63;
    const int l15 = lane & 15, quad = lane >> 4;
    const int le = lane >> 2, sub = lane & 3;
    const int t = blockIdx.x * 4 + w;
    if (t >= NN / 16) return;                      // 3125 waves exactly

    // gather (fully coalesced): [hb | tmsgb] -> S[16][128]; zero tmsgb after
    {
        unsigned short* Srow = &S[w][le][0];
        const int n = t * 16 + le;
        const unsigned short* hr = hb + (size_t)n * HH + sub * 16;
        *(uint4*)&Srow[sub * 16]     = *(const uint4*)(hr);
        *(uint4*)&Srow[sub * 16 + 8] = *(const uint4*)(hr + 8);
        unsigned short* tm = tmsgb + (size_t)n * HH + sub * 16;
        *(uint4*)&Srow[64 + sub * 16]     = *(const uint4*)(tm);
        *(uint4*)&Srow[64 + sub * 16 + 8] = *(const uint4*)(tm + 8);
        const uint4 z = {0u, 0u, 0u, 0u};
        *(uint4*)(tm)     = z;
        *(uint4*)(tm + 8) = z;
    }
    // x update: one lane per node; zero sum_f after
    if (lane < 16) {
        const int nn = t * 16 + lane;
        const float cn = fmaxf((float)deg[nn], 1.0f);
        const float rc = __builtin_amdgcn_rcpf(cn);
        #pragma unroll
        for (int d3 = 0; d3 < 3; ++d3) {
            float tf = sum_f[3 * nn + d3] * rc;
            tf = fminf(fmaxf(tf, -100.0f), 100.0f);
            x[3 * nn + d3] += tf;
            x4[4 * nn + d3] += tf;
            sum_f[3 * nn + d3] = 0.0f;
        }
    }
    WFENCE();

    // GEMM1: [16x128] @ nW1[128x64] -> SiLU -> alias cols 0..63
    bf16x8 af[4];
    #pragma unroll
    for (int s = 0; s < 4; ++s)
        af[s] = *(const bf16x8*)&S[w][l15][s * 32 + quad * 8];
    WFENCE();
    float nb1v[4], nb2v[4];
    #pragma unroll
    for (int nt = 0; nt < 4; ++nt) {
        nb1v[nt] = nb1[nt * 16 + l15];
        nb2v[nt] = nb2[nt * 16 + l15];
    }
    #pragma unroll
    for (int nt = 0; nt < 4; ++nt) {
        f32x4 a = {0.f, 0.f, 0.f, 0.f};
        #pragma unroll
        for (int s = 0; s < 4; ++s) {
            bf16x8 bf = *(const bf16x8*)(nw1b + ((s * 4 + nt) * 64 + lane) * 8);
            a = __builtin_amdgcn_mfma_f32_16x16x32_bf16(af[s], bf, a, 0, 0, 0);
        }
        #pragma unroll
        for (int rr = 0; rr < 4; ++rr)
            S[w][quad * 4 + rr][nt * 16 + l15] = bfb(silu_f(a[rr] + nb1v[nt]));
    }
    WFENCE();

    // GEMM2: [16x64] @ nW2[64x64] -> h (no act)
    bf16x8 a2[2];
    #pragma unroll
    for (int s = 0; s < 2; ++s)
        a2[s] = *(const bf16x8*)&S[w][l15][s * 32 + quad * 8];
    #pragma unroll
    for (int nt = 0; nt < 4; ++nt) {
        f32x4 m = {0.f, 0.f, 0.f, 0.f};
        #pragma unroll
        for (int s = 0; s < 2; ++s) {
            bf16x8 bf = *(const bf16x8*)(nw2b + ((s * 4 + nt) * 64 + lane) * 8);
            m = __builtin_amdgcn_mfma_f32_16x16x32_bf16(a2[s], bf, m, 0, 0, 0);
        }
        #pragma unroll
        for (int rr = 0; rr < 4; ++rr) {
            const float v = m[rr] + nb2v[nt];
            const size_t nd = (size_t)(t * 16 + quad * 4 + rr) * HH + nt * 16 + l15;
            h[nd] = v;
            hb[nd] = bfb(v);
        }
    }
}

extern "C" void kernel_launch(void* const* d_in, const int* in_sizes, int n_in,
                              void* d_out, int out_size, void* d_ws, size_t ws_size,
                              hipStream_t stream) {
    const float* x_in  = (const float*)d_in[0];
    const float* h_in  = (const float*)d_in[1];
    const int*   row   = (const int*)d_in[2];
    const int*   col   = (const int*)d_in[3];
    const float* efea  = (const float*)d_in[4];
    const float* emb_W = (const float*)d_in[5];
    const float* emb_b = (const float*)d_in[6];
    const float* eW1   = (const float*)d_in[7];
    const float* eb1   = (const float*)d_in[8];
    const float* eW2   = (const float*)d_in[9];
    const float* eb2   = (const float*)d_in[10];
    const float* cW1   = (const float*)d_in[11];
    const float* cb1   = (const float*)d_in[12];
    const float* cW2   = (const float*)d_in[13];
    const float* cb2   = (const float*)d_in[14];
    const float* nW1   = (const float*)d_in[15];
    const float* nb1   = (const float*)d_in[16];
    const float* nW2   = (const float*)d_in[17];
    const float* nb2   = (const float*)d_in[18];

    float* out = (float*)d_out;
    float* xo = out;                 // N*3
    float* ho = out + NN * 3;        // N*64

    // workspace layout (16B-aligned segments)
    char* wsb = (char*)d_ws;
    float* sum_f = (float*)wsb;                                  //    600,000 B
    unsigned short* tmsgb = (unsigned short*)(wsb + 600000);     //  6,400,000 B
    unsigned short* efs = (unsigned short*)(wsb + 7000000);      // 12,800,000 B
    unsigned short* hb  = (unsigned short*)(wsb + 19800000);     //  6,400,000 B
    unsigned short* wsW = (unsigned short*)(wsb + 26200000);     //    122,880 B
    int* deg    = (int*)(wsb + 26322880);                        //    200,000 B
    int* cur    = (int*)(wsb + 26522880);                        //    200,000 B
    int2* rc    = (int2*)(wsb + 26722880);                       //  6,400,000 B
    float* x4   = (float*)(wsb + 33122880);                      //    800,000 B
    int* bsum   = (int*)(wsb + 33922880);                        //        800 B
    int* boff   = (int*)(wsb + 33923680);                        //        800 B

    // zero deg, then fused setup (hist + swizzle + embed + zero + x copies)
    hipMemsetAsync(deg, 0, 200000, stream);
    setup_kernel<<<17917, 256, 0, stream>>>(
        row, deg,
        eW1, eW2, cW1, nW1, nW2, wsW,
        h_in, emb_W, emb_b, ho, hb,
        wsb, x_in, xo, x4);
    // row scan + counting sort
    scanA_kernel<<<200, 256, 0, stream>>>(deg, bsum);
    scanB_kernel<<<1, 256, 0, stream>>>(bsum, boff);
    scanC_kernel<<<200, 256, 0, stream>>>(deg, boff, cur);
    fill_kernel<<<MM / 256, 256, 0, stream>>>(row, col, efea, cur, rc, efs);

    for (int i = 0; i < 2; ++i) {
        const unsigned short* L = wsW + i * 30720;
        edge_mfma_kernel<<<NB_EDGE, 256, 0, stream>>>(
            x4, hb, rc, efs,
            L, L + 10240, L + 14336,
            eb1 + i * 64, eb2 + i * 64, cb1 + i * 64, cW2 + i * 64, cb2 + i,
            sum_f, tmsgb);
        node_mfma_kernel<<<(NN / 16 + 3) / 4, 256, 0, stream>>>(
            xo, x4, ho, hb, sum_f, deg, tmsgb,
            L + 18432, L + 26624, nb1 + i * 64, nb2 + i * 64);
    }
}

// Round 7
// 418.424 us; speedup vs baseline: 1.3539x; 1.0136x over previous
//
#include <hip/hip_runtime.h>
#include <math.h>

#define NN 50000
#define MM 800000
#define HH 64
#define NB_EDGE 1792
#define NTILE 12500                 // MM / 64 edges per block-tile

typedef short bf16x8 __attribute__((ext_vector_type(8)));
typedef float f32x4  __attribute__((ext_vector_type(4)));

// per-wave LDS fence: all LDS regions are wave-private; lockstep + lgkmcnt
// drain replaces __syncthreads. NOTE: waits lgkmcnt only -- global loads
// (vmcnt) issued before the fence stay in flight across it (pipeline relies
// on this).
#define WFENCE() asm volatile("s_waitcnt lgkmcnt(0)" ::: "memory")

__device__ __forceinline__ float silu_f(float v) {
    return v * __builtin_amdgcn_rcpf(1.0f + __expf(-v));
}
// round-half-up fp32 -> bf16 bits (0.5 ulp max)
__device__ __forceinline__ unsigned short bfb(float a) {
    return (unsigned short)((__float_as_uint(a) + 0x8000u) >> 16);
}
// pack two f32 -> one u32 of 2 bf16 (low = lo, high = hi), single VALU op
__device__ __forceinline__ unsigned cvtpk(float lo, float hi) {
    unsigned r;
    asm("v_cvt_pk_bf16_f32 %0, %1, %2" : "=v"(r) : "v"(lo), "v"(hi));
    return r;
}
// pack two f32 -> bf16x2 via v_perm (low = a, high = b)
__device__ __forceinline__ unsigned pk2(float a, float b) {
    return __builtin_amdgcn_perm(__float_as_uint(b) + 0x8000u,
                                 __float_as_uint(a) + 0x8000u, 0x07060302u);
}
__device__ __forceinline__ float b2f(unsigned short s) {
    return __uint_as_float((unsigned)s << 16);
}
// packed bf16x2 atomic add
__device__ __forceinline__ void atomic_pk_bf16(unsigned short* addr, unsigned pk) {
    asm volatile("global_atomic_pk_add_bf16 %0, %1, off"
                 :: "v"((unsigned long long)(size_t)addr), "v"(pk) : "memory");
}

// ---------------- fused setup ----------------
// blocks [0,3125): deg histogram
// blocks [3125,3365): weight pre-swizzle (per layer 30720 shorts)
// blocks [3365,15865): embedding
// blocks [15865,17574): zero sum_f+tmsgb (7,000,000 B)
// blocks [17574,17721): copy x_in -> xo (uint4)
// blocks [17721,17917): build padded x4 mirror
__global__ __launch_bounds__(256) void setup_kernel(
    const int* __restrict__ row, int* __restrict__ deg,
    const float* __restrict__ eW1, const float* __restrict__ eW2,
    const float* __restrict__ cW1, const float* __restrict__ nW1,
    const float* __restrict__ nW2, unsigned short* __restrict__ wsW,
    const float* __restrict__ h_in, const float* __restrict__ emb_W,
    const float* __restrict__ emb_b, float* __restrict__ h_out,
    unsigned short* __restrict__ hb,
    char* __restrict__ zbase, const float* __restrict__ x_in,
    float* __restrict__ xo, float* __restrict__ x4)
{
    const int b = blockIdx.x;
    if (b < 3125) {
        const int e = b * 256 + threadIdx.x;
        atomicAdd(&deg[row[e]], 1);
    } else if (b < 3365) {
        const int i = (b - 3125) * 256 + threadIdx.x;     // 0 .. 61439
        const int layer = i / 30720;
        const int rem = i - layer * 30720;
        float val;
        if (rem < 10240) {
            const int j = rem & 7, lane = (rem >> 3) & 63, nt = (rem >> 9) & 3, s = rem >> 11;
            const int kp = s * 32 + ((lane >> 4) << 3) + j;
            const int n  = nt * 16 + (lane & 15);
            if (kp > 136) val = 0.0f;
            else {
                const int k = (kp == 136) ? 0 : kp + 1;   // k'=136 is the r2 row
                val = eW1[layer * 137 * 64 + k * 64 + n];
            }
        } else if (rem < 14336) {
            const int r2 = rem - 10240;
            const int j = r2 & 7, lane = (r2 >> 3) & 63, nt = (r2 >> 9) & 3, s = r2 >> 11;
            val = eW2[layer * 4096 + (s * 32 + ((lane >> 4) << 3) + j) * 64 + nt * 16 + (lane & 15)];
        } else if (rem < 18432) {
            const int r3 = rem - 14336;
            const int j = r3 & 7, lane = (r3 >> 3) & 63, nt = (r3 >> 9) & 3, s = r3 >> 11;
            val = cW1[layer * 4096 + (s * 32 + ((lane >> 4) << 3) + j) * 64 + nt * 16 + (lane & 15)];
        } else if (rem < 26624) {
            const int r4 = rem - 18432;
            const int j = r4 & 7, lane = (r4 >> 3) & 63, nt = (r4 >> 9) & 3, s = r4 >> 11;
            const int kp = s * 32 + ((lane >> 4) << 3) + j;      // < 128
            val = nW1[layer * 8192 + kp * 64 + nt * 16 + (lane & 15)];
        } else {
            const int r5 = rem - 26624;
            const int j = r5 & 7, lane = (r5 >> 3) & 63, nt = (r5 >> 9) & 3, s = r5 >> 11;
            val = nW2[layer * 4096 + (s * 32 + ((lane >> 4) << 3) + j) * 64 + nt * 16 + (lane & 15)];
        }
        wsW[i] = bfb(val);
    } else if (b < 15865) {
        const int idx = (b - 3365) * 256 + threadIdx.x;   // over N*64
        const int n = idx >> 6, j = idx & 63;
        float acc = emb_b[j];
        #pragma unroll
        for (int k = 0; k < 16; ++k)
            acc += h_in[n * 16 + k] * emb_W[k * HH + j];
        h_out[idx] = acc;
        hb[idx] = bfb(acc);
    } else if (b < 17574) {
        const int t = (b - 15865) * 256 + threadIdx.x;
        if (t < 437500) {                                  // 7,000,000 / 16
            const uint4 z = {0u, 0u, 0u, 0u};
            *(uint4*)(zbase + (size_t)t * 16) = z;
        }
    } else if (b < 17721) {
        const int t = (b - 17574) * 256 + threadIdx.x;
        if (t < 37500)                                     // N*3 floats / 4
            ((uint4*)xo)[t] = ((const uint4*)x_in)[t];
    } else {
        const int n = (b - 17721) * 256 + threadIdx.x;
        if (n < NN) {
            float4 v;
            v.x = x_in[3 * n + 0];
            v.y = x_in[3 * n + 1];
            v.z = x_in[3 * n + 2];
            v.w = 0.0f;
            ((float4*)x4)[n] = v;
        }
    }
}

// parallel scan over NN, phase A: 200 blocks x 250-node chunks -> blocksum
__global__ __launch_bounds__(256) void scanA_kernel(const int* __restrict__ deg,
                                                    int* __restrict__ bsum) {
    __shared__ int ps[256];
    const int t = threadIdx.x;
    const int base = blockIdx.x * 250;
    int v = (t < 250) ? deg[base + t] : 0;
    ps[t] = v;
    __syncthreads();
    for (int off = 1; off < 256; off <<= 1) {
        const int u = (t >= off) ? ps[t - off] : 0;
        __syncthreads();
        ps[t] += u;
        __syncthreads();
    }
    if (t == 255) bsum[blockIdx.x] = ps[255];
}

// phase B: exclusive scan of 200 blocksums (single small block)
__global__ __launch_bounds__(256) void scanB_kernel(const int* __restrict__ bsum,
                                                    int* __restrict__ boff) {
    __shared__ int ps[256];
    const int t = threadIdx.x;
    int v = (t < 200) ? bsum[t] : 0;
    ps[t] = v;
    __syncthreads();
    for (int off = 1; off < 256; off <<= 1) {
        const int u = (t >= off) ? ps[t - off] : 0;
        __syncthreads();
        ps[t] += u;
        __syncthreads();
    }
    if (t < 200) boff[t] = ps[t] - v;     // exclusive
}

// phase C: per-chunk exclusive scan + global offset -> cur
__global__ __launch_bounds__(256) void scanC_kernel(const int* __restrict__ deg,
                                                    const int* __restrict__ boff,
                                                    int* __restrict__ cur) {
    __shared__ int ps[256];
    const int t = threadIdx.x;
    const int base = blockIdx.x * 250;
    int v = (t < 250) ? deg[base + t] : 0;
    ps[t] = v;
    __syncthreads();
    for (int off = 1; off < 256; off <<= 1) {
        const int u = (t >= off) ? ps[t - off] : 0;
        __syncthreads();
        ps[t] += u;
        __syncthreads();
    }
    if (t < 250)
        cur[base + t] = boff[blockIdx.x] + ps[t] - v;   // exclusive prefix
}

// one-pass counting-sort fill: rc (int2 interleaved) + efs in row-sorted order
__global__ __launch_bounds__(256) void fill_kernel(
    const int* __restrict__ row, const int* __restrict__ col,
    const float* __restrict__ efea, int* __restrict__ cur,
    int2* __restrict__ rc, unsigned short* __restrict__ efs)
{
    const int e = blockIdx.x * 256 + threadIdx.x;
    const int r = row[e];
    const int pos = atomicAdd(&cur[r], 1);
    int2 v; v.x = r; v.y = col[e];
    rc[pos] = v;                                       // one 8B scatter
    const float4* ef = (const float4*)(efea + (size_t)e * 8);
    const float4 e0 = ef[0], e1 = ef[1];
    uint4 ue = { pk2(e0.x, e0.y), pk2(e0.z, e0.w), pk2(e1.x, e1.y), pk2(e1.z, e1.w) };
    *(uint4*)(efs + (size_t)pos * 8) = ue;
}

// ---------------- MFMA edge kernel: swapped operands + pipelined gather -----
// Swapped MFMAs (R6): lane (l15,quad) holds D[e=l15][n=nt*16+quad*4+rr];
// biases folded in via ones-fragment K-slices. R7 changes:
//  1. S row stride 80 -> 72 shorts (36 dwords): row-indexed b128 reads / 8B
//     writes go from 4-way to 2-way bank aliasing (2-way is free, m136).
//  2. Gather software-pipelined one tile deep REUSING the af registers: after
//     GEMM1 consumes af0..af4 they are dead; the next tile's hb/efs loads are
//     issued into the same variables between G1 and the fence, then fly
//     across G2+G3+flush (lgkmcnt fences don't drain vmcnt). rc is loaded one
//     iteration early (rcn). cw2 moved to LDS to free 16 VGPRs of slack.
__global__ __launch_bounds__(256, 4) void edge_mfma_kernel(
    const float* __restrict__ x4, const unsigned short* __restrict__ hb,
    const int2* __restrict__ rc, const unsigned short* __restrict__ efs,
    const unsigned short* __restrict__ w1b, const unsigned short* __restrict__ w2b,
    const unsigned short* __restrict__ cw1b,
    const float* __restrict__ b1, const float* __restrict__ b2,
    const float* __restrict__ cb1, const float* __restrict__ cw2,
    const float* __restrict__ cb2,
    float* __restrict__ sum_f, unsigned short* __restrict__ tmsgb)
{
    __shared__ __align__(16) unsigned short S[4][16][72];  // [0,64)=H1/msg, [64,66)=cm f32
    __shared__ float RV[4][16][4];
    __shared__ int   RI[4][16];
    __shared__ __align__(16) unsigned short WS[14336];
    __shared__ __align__(16) float CW2S[64];
    // WS shorts: [0,4096)=w2 s0,s1   [4096,6144)=w2 bias slice
    //            [6144,10240)=cw1 s0,s1  [10240,12288)=cw1 bias slice
    //            [12288,14336)=w1 slice4 (kp137 patched with b1)

    const int tid = threadIdx.x;
    const int w = tid >> 6, lane = tid & 63;
    const int l15 = lane & 15, quad = lane >> 4;

    // stage weights + bias slices into LDS, block-shared
    {
        const uint4* s2 = (const uint4*)w2b;
        const uint4* s3 = (const uint4*)cw1b;
        const uint4* s4 = (const uint4*)w1b;   // slice4 = uint4 idx [1024,1280)
        uint4* dst = (uint4*)WS;
        dst[tid]        = s2[tid];
        dst[256 + tid]  = s2[256 + tid];
        dst[768 + tid]  = s3[tid];
        dst[1024 + tid] = s3[256 + tid];
        const int ln = tid & 63, ntb = tid >> 6;
        uint4 z4 = s4[1024 + tid];
        if ((ln >> 4) == 1)    // quad==1, j==1 slot = kp137 (high half of .x)
            z4.x = (z4.x & 0x0000FFFFu) | ((unsigned)bfb(b1[ntb * 16 + (ln & 15)]) << 16);
        dst[1536 + tid] = z4;
        uint4 zb = {0u, 0u, 0u, 0u};
        if ((ln >> 4) == 0) zb.x = (unsigned)bfb(b2[ntb * 16 + (ln & 15)]);
        dst[512 + tid] = zb;
        uint4 zc = {0u, 0u, 0u, 0u};
        if ((ln >> 4) == 0) zc.x = (unsigned)bfb(cb1[ntb * 16 + (ln & 15)]);
        dst[1280 + tid] = zc;
        if (tid < 64) CW2S[tid] = cw2[tid];
    }

    // hoist W1 slices 0..3 into registers (loop-invariant; AGPR-parked, 64)
    bf16x8 w1f[4][4];
    #pragma unroll
    for (int s = 0; s < 4; ++s)
        #pragma unroll
        for (int nt = 0; nt < 4; ++nt)
            w1f[s][nt] = *(const bf16x8*)(w1b + ((s * 4 + nt) * 64 + lane) * 8);

    const float cb2s = cb2[0];

    // ones B-fragment: B[k=0][e]=1 for all e (bias K-slice driver)
    bf16x8 onef = {0, 0, 0, 0, 0, 0, 0, 0};
    if (quad == 0) onef[0] = (short)0x3F80;

    __syncthreads();   // WS/CW2S visible to all 4 waves

    // ---- pipeline prologue: rc for tile 0 and 1, payload for tile 0 ----
    int bt  = blockIdx.x;
    int btn = bt + NB_EDGE;
    int2 rcv = rc[(bt * 4 + w) * 16 + l15];
    int2 rcn = rc[((btn < NTILE ? btn : bt) * 4 + w) * 16 + l15];
    bf16x8 af0, af1, af2, af3;
    bf16x8 af4 = {0, 0, 0, 0, 0, 0, 0, 0};
    {
        const unsigned short* hr = hb + (size_t)rcv.x * HH + quad * 8;
        const unsigned short* hc = hb + (size_t)rcv.y * HH + quad * 8;
        af0 = *(const bf16x8*)(hr);
        af1 = *(const bf16x8*)(hr + 32);
        af2 = *(const bf16x8*)(hc);
        af3 = *(const bf16x8*)(hc + 32);
        if (quad == 0)
            af4 = *(const bf16x8*)(efs + (size_t)((bt * 4 + w) * 16 + l15) * 8);
    }

    while (bt < NTILE) {
        // ---- consume: per-tile scalars (x4 read not prefetched; its latency
        // hides under G1's first 16 MFMAs since af4 only feeds the last slice)
        if (quad == 0) {
            RI[w][l15] = rcv.x;
        } else if (quad == 1) {
            const float4 xr = ((const float4*)x4)[rcv.x];
            const float4 xc = ((const float4*)x4)[rcv.y];
            const float rx = xr.x - xc.x;
            const float ry = xr.y - xc.y;
            const float rz = xr.z - xc.z;
            RV[w][l15][0] = rx; RV[w][l15][1] = ry; RV[w][l15][2] = rz;
            af4[0] = (short)bfb(rx * rx + ry * ry + rz * rz);
            af4[1] = (short)0x3F80;   // kp=137 constant-1 -> b1 bias row
        }

        // ---- GEMM1 swapped: lane holds H1[l15][nt*16+quad*4+rr] ----
        #pragma unroll
        for (int nt = 0; nt < 4; ++nt) {
            f32x4 a = {0.f, 0.f, 0.f, 0.f};
            a = __builtin_amdgcn_mfma_f32_16x16x32_bf16(w1f[0][nt], af0, a, 0, 0, 0);
            a = __builtin_amdgcn_mfma_f32_16x16x32_bf16(w1f[1][nt], af1, a, 0, 0, 0);
            a = __builtin_amdgcn_mfma_f32_16x16x32_bf16(w1f[2][nt], af2, a, 0, 0, 0);
            a = __builtin_amdgcn_mfma_f32_16x16x32_bf16(w1f[3][nt], af3, a, 0, 0, 0);
            {
                bf16x8 b4 = *(const bf16x8*)&WS[12288 + (nt * 64 + lane) * 8];
                a = __builtin_amdgcn_mfma_f32_16x16x32_bf16(b4, af4, a, 0, 0, 0);
            }
            uint2 pkv;
            pkv.x = cvtpk(silu_f(a[0]), silu_f(a[1]));
            pkv.y = cvtpk(silu_f(a[2]), silu_f(a[3]));
            *(uint2*)&S[w][l15][nt * 16 + quad * 4] = pkv;   // row=e, cols n..n+3
        }

        // ---- issue next tile's payload into the now-dead af regs ----
        {
            const int pn = ((btn < NTILE ? btn : bt) * 4 + w) * 16 + l15;
            const unsigned short* hr = hb + (size_t)rcn.x * HH + quad * 8;
            const unsigned short* hc = hb + (size_t)rcn.y * HH + quad * 8;
            af0 = *(const bf16x8*)(hr);
            af1 = *(const bf16x8*)(hr + 32);
            af2 = *(const bf16x8*)(hc);
            af3 = *(const bf16x8*)(hc + 32);
            if (quad == 0)
                af4 = *(const bf16x8*)(efs + (size_t)pn * 8);
        }
        const int btn2 = btn + NB_EDGE;
        const int2 rcn2 = rc[((btn2 < NTILE ? btn2 : btn) * 4 + w) * 16 + l15];
        WFENCE();

        // ---- GEMM2 swapped: B-frags = H1[l15][s*32+quad*8..] from S ----
        bf16x8 h1f0 = *(const bf16x8*)&S[w][l15][quad * 8];
        bf16x8 h1f1 = *(const bf16x8*)&S[w][l15][32 + quad * 8];
        WFENCE();   // frags in regs before msg overwrites
        #pragma unroll
        for (int nt = 0; nt < 4; ++nt) {
            f32x4 m = {0.f, 0.f, 0.f, 0.f};
            {
                bf16x8 wf = *(const bf16x8*)&WS[((0 * 4 + nt) * 64 + lane) * 8];
                m = __builtin_amdgcn_mfma_f32_16x16x32_bf16(wf, h1f0, m, 0, 0, 0);
            }
            {
                bf16x8 wf = *(const bf16x8*)&WS[((1 * 4 + nt) * 64 + lane) * 8];
                m = __builtin_amdgcn_mfma_f32_16x16x32_bf16(wf, h1f1, m, 0, 0, 0);
            }
            {
                bf16x8 wb = *(const bf16x8*)&WS[4096 + (nt * 64 + lane) * 8];
                m = __builtin_amdgcn_mfma_f32_16x16x32_bf16(wb, onef, m, 0, 0, 0);
            }
            uint2 pkv;
            pkv.x = cvtpk(silu_f(m[0]), silu_f(m[1]));
            pkv.y = cvtpk(silu_f(m[2]), silu_f(m[3]));
            *(uint2*)&S[w][l15][nt * 16 + quad * 4] = pkv;   // msg[e][n]
        }
        WFENCE();

        // ---- GEMM3 swapped: c1[l15][n]; lane-local dot with cw2 (LDS) ----
        bf16x8 mf0 = *(const bf16x8*)&S[w][l15][quad * 8];
        bf16x8 mf1 = *(const bf16x8*)&S[w][l15][32 + quad * 8];
        float pr = 0.f;
        #pragma unroll
        for (int nt = 0; nt < 4; ++nt) {
            f32x4 q3 = {0.f, 0.f, 0.f, 0.f};
            {
                bf16x8 wf = *(const bf16x8*)&WS[6144 + ((0 * 4 + nt) * 64 + lane) * 8];
                q3 = __builtin_amdgcn_mfma_f32_16x16x32_bf16(wf, mf0, q3, 0, 0, 0);
            }
            {
                bf16x8 wf = *(const bf16x8*)&WS[6144 + ((1 * 4 + nt) * 64 + lane) * 8];
                q3 = __builtin_amdgcn_mfma_f32_16x16x32_bf16(wf, mf1, q3, 0, 0, 0);
            }
            {
                bf16x8 wb = *(const bf16x8*)&WS[10240 + (nt * 64 + lane) * 8];
                q3 = __builtin_amdgcn_mfma_f32_16x16x32_bf16(wb, onef, q3, 0, 0, 0);
            }
            const float4 cwv = *(const float4*)&CW2S[nt * 16 + quad * 4];
            pr += silu_f(q3[0]) * cwv.x;
            pr += silu_f(q3[1]) * cwv.y;
            pr += silu_f(q3[2]) * cwv.z;
            pr += silu_f(q3[3]) * cwv.w;
        }
        pr += __shfl_xor(pr, 16, 64);    // reduce over the 4 quads of edge l15
        pr += __shfl_xor(pr, 32, 64);
        if (quad == 0) *(float*)&S[w][l15][64] = pr + cb2s;
        WFENCE();

        // ---- segmented flush: rows sorted by RI within the tile ----
        if (lane < 32) {   // msg -> tmsgb: lane owns cols {2l, 2l+1}, pk atomic
            unsigned both = *(const unsigned*)&S[w][0][2 * lane];
            float ax = b2f((unsigned short)(both & 0xffffu));
            float ay = b2f((unsigned short)(both >> 16));
            int cur_r = RI[w][0];
            #pragma unroll
            for (int g = 1; g < 16; ++g) {
                const int ri = RI[w][g];
                unsigned bv = *(const unsigned*)&S[w][g][2 * lane];
                const float vx = b2f((unsigned short)(bv & 0xffffu));
                const float vy = b2f((unsigned short)(bv >> 16));
                if (ri != cur_r) {
                    atomic_pk_bf16(&tmsgb[(size_t)cur_r * HH + 2 * lane], pk2(ax, ay));
                    ax = 0.f; ay = 0.f; cur_r = ri;
                }
                ax += vx; ay += vy;
            }
            atomic_pk_bf16(&tmsgb[(size_t)cur_r * HH + 2 * lane], pk2(ax, ay));
        } else if ((lane & 31) < 3) {   // f = rij*cm -> sum_f (fp32, tiny)
            const int sl = lane & 31;
            float acc = RV[w][0][sl] * (*(const float*)&S[w][0][64]);
            int cur_r = RI[w][0];
            #pragma unroll
            for (int g = 1; g < 16; ++g) {
                const int ri = RI[w][g];
                const float v = RV[w][g][sl] * (*(const float*)&S[w][g][64]);
                if (ri != cur_r) {
                    atomicAdd(&sum_f[3 * cur_r + sl], acc);
                    acc = 0.f; cur_r = ri;
                }
                acc += v;
            }
            atomicAdd(&sum_f[3 * cur_r + sl], acc);
        }
        WFENCE();   // flush reads drained before next iter's S writes (WAR)

        // ---- rotate pipeline state ----
        bt = btn; btn = btn2; rcv = rcn; rcn = rcn2;
    }
}

// ---------------- MFMA node kernel: 16 nodes per wave ----------------
// Reads bf16 tmsgb directly; zeroes tmsgb/sum_f after use (next layer's init).
// Updates both xo (output) and x4 (padded mirror for next layer's edge pass).
__global__ __launch_bounds__(256) void node_mfma_kernel(
    float* __restrict__ x, float* __restrict__ x4, float* __restrict__ h,
    unsigned short* __restrict__ hb,
    float* __restrict__ sum_f, const int* __restrict__ deg,
    unsigned short* __restrict__ tmsgb,
    const unsigned short* __restrict__ nw1b, const unsigned short* __restrict__ nw2b,
    const float* __restrict__ nb1, const float* __restrict__ nb2)
{
    __shared__ __align__(16) unsigned short S[4][16][136];
    const int tid = threadIdx.x;
    const int w = tid >> 6, lane = tid & 63;
    const int l15 = lane & 15, quad = lane >> 4;
    const int le = lane >> 2, sub = lane & 3;
    const int t = blockIdx.x * 4 + w;
    if (t >= NN / 16) return;                      // 3125 waves exactly

    // gather (fully coalesced): [hb | tmsgb] -> S[16][128]; zero tmsgb after
    {
        unsigned short* Srow = &S[w][le][0];
        const int n = t * 16 + le;
        const unsigned short* hr = hb + (size_t)n * HH + sub * 16;
        *(uint4*)&Srow[sub * 16]     = *(const uint4*)(hr);
        *(uint4*)&Srow[sub * 16 + 8] = *(const uint4*)(hr + 8);
        unsigned short* tm = tmsgb + (size_t)n * HH + sub * 16;
        *(uint4*)&Srow[64 + sub * 16]     = *(const uint4*)(tm);
        *(uint4*)&Srow[64 + sub * 16 + 8] = *(const uint4*)(tm + 8);
        const uint4 z = {0u, 0u, 0u, 0u};
        *(uint4*)(tm)     = z;
        *(uint4*)(tm + 8) = z;
    }
    // x update: one lane per node; zero sum_f after
    if (lane < 16) {
        const int nn = t * 16 + lane;
        const float cn = fmaxf((float)deg[nn], 1.0f);
        const float rc = __builtin_amdgcn_rcpf(cn);
        #pragma unroll
        for (int d3 = 0; d3 < 3; ++d3) {
            float tf = sum_f[3 * nn + d3] * rc;
            tf = fminf(fmaxf(tf, -100.0f), 100.0f);
            x[3 * nn + d3] += tf;
            x4[4 * nn + d3] += tf;
            sum_f[3 * nn + d3] = 0.0f;
        }
    }
    WFENCE();

    // GEMM1: [16x128] @ nW1[128x64] -> SiLU -> alias cols 0..63
    bf16x8 af[4];
    #pragma unroll
    for (int s = 0; s < 4; ++s)
        af[s] = *(const bf16x8*)&S[w][l15][s * 32 + quad * 8];
    WFENCE();
    float nb1v[4], nb2v[4];
    #pragma unroll
    for (int nt = 0; nt < 4; ++nt) {
        nb1v[nt] = nb1[nt * 16 + l15];
        nb2v[nt] = nb2[nt * 16 + l15];
    }
    #pragma unroll
    for (int nt = 0; nt < 4; ++nt) {
        f32x4 a = {0.f, 0.f, 0.f, 0.f};
        #pragma unroll
        for (int s = 0; s < 4; ++s) {
            bf16x8 bf = *(const bf16x8*)(nw1b + ((s * 4 + nt) * 64 + lane) * 8);
            a = __builtin_amdgcn_mfma_f32_16x16x32_bf16(af[s], bf, a, 0, 0, 0);
        }
        #pragma unroll
        for (int rr = 0; rr < 4; ++rr)
            S[w][quad * 4 + rr][nt * 16 + l15] = bfb(silu_f(a[rr] + nb1v[nt]));
    }
    WFENCE();

    // GEMM2: [16x64] @ nW2[64x64] -> h (no act)
    bf16x8 a2[2];
    #pragma unroll
    for (int s = 0; s < 2; ++s)
        a2[s] = *(const bf16x8*)&S[w][l15][s * 32 + quad * 8];
    #pragma unroll
    for (int nt = 0; nt < 4; ++nt) {
        f32x4 m = {0.f, 0.f, 0.f, 0.f};
        #pragma unroll
        for (int s = 0; s < 2; ++s) {
            bf16x8 bf = *(const bf16x8*)(nw2b + ((s * 4 + nt) * 64 + lane) * 8);
            m = __builtin_amdgcn_mfma_f32_16x16x32_bf16(a2[s], bf, m, 0, 0, 0);
        }
        #pragma unroll
        for (int rr = 0; rr < 4; ++rr) {
            const float v = m[rr] + nb2v[nt];
            const size_t nd = (size_t)(t * 16 + quad * 4 + rr) * HH + nt * 16 + l15;
            h[nd] = v;
            hb[nd] = bfb(v);
        }
    }
}

extern "C" void kernel_launch(void* const* d_in, const int* in_sizes, int n_in,
                              void* d_out, int out_size, void* d_ws, size_t ws_size,
                              hipStream_t stream) {
    const float* x_in  = (const float*)d_in[0];
    const float* h_in  = (const float*)d_in[1];
    const int*   row   = (const int*)d_in[2];
    const int*   col   = (const int*)d_in[3];
    const float* efea  = (const float*)d_in[4];
    const float* emb_W = (const float*)d_in[5];
    const float* emb_b = (const float*)d_in[6];
    const float* eW1   = (const float*)d_in[7];
    const float* eb1   = (const float*)d_in[8];
    const float* eW2   = (const float*)d_in[9];
    const float* eb2   = (const float*)d_in[10];
    const float* cW1   = (const float*)d_in[11];
    const float* cb1   = (const float*)d_in[12];
    const float* cW2   = (const float*)d_in[13];
    const float* cb2   = (const float*)d_in[14];
    const float* nW1   = (const float*)d_in[15];
    const float* nb1   = (const float*)d_in[16];
    const float* nW2   = (const float*)d_in[17];
    const float* nb2   = (const float*)d_in[18];

    float* out = (float*)d_out;
    float* xo = out;                 // N*3
    float* ho = out + NN * 3;        // N*64

    // workspace layout (16B-aligned segments)
    char* wsb = (char*)d_ws;
    float* sum_f = (float*)wsb;                                  //    600,000 B
    unsigned short* tmsgb = (unsigned short*)(wsb + 600000);     //  6,400,000 B
    unsigned short* efs = (unsigned short*)(wsb + 7000000);      // 12,800,000 B
    unsigned short* hb  = (unsigned short*)(wsb + 19800000);     //  6,400,000 B
    unsigned short* wsW = (unsigned short*)(wsb + 26200000);     //    122,880 B
    int* deg    = (int*)(wsb + 26322880);                        //    200,000 B
    int* cur    = (int*)(wsb + 26522880);                        //    200,000 B
    int2* rc    = (int2*)(wsb + 26722880);                       //  6,400,000 B
    float* x4   = (float*)(wsb + 33122880);                      //    800,000 B
    int* bsum   = (int*)(wsb + 33922880);                        //        800 B
    int* boff   = (int*)(wsb + 33923680);                        //        800 B

    // zero deg, then fused setup (hist + swizzle + embed + zero + x copies)
    hipMemsetAsync(deg, 0, 200000, stream);
    setup_kernel<<<17917, 256, 0, stream>>>(
        row, deg,
        eW1, eW2, cW1, nW1, nW2, wsW,
        h_in, emb_W, emb_b, ho, hb,
        wsb, x_in, xo, x4);
    // row scan + counting sort
    scanA_kernel<<<200, 256, 0, stream>>>(deg, bsum);
    scanB_kernel<<<1, 256, 0, stream>>>(bsum, boff);
    scanC_kernel<<<200, 256, 0, stream>>>(deg, boff, cur);
    fill_kernel<<<MM / 256, 256, 0, stream>>>(row, col, efea, cur, rc, efs);

    for (int i = 0; i < 2; ++i) {
        const unsigned short* L = wsW + i * 30720;
        edge_mfma_kernel<<<NB_EDGE, 256, 0, stream>>>(
            x4, hb, rc, efs,
            L, L + 10240, L + 14336,
            eb1 + i * 64, eb2 + i * 64, cb1 + i * 64, cW2 + i * 64, cb2 + i,
            sum_f, tmsgb);
        node_mfma_kernel<<<(NN / 16 + 3) / 4, 256, 0, stream>>>(
            xo, x4, ho, hb, sum_f, deg, tmsgb,
            L + 18432, L + 26624, nb1 + i * 64, nb2 + i * 64);
    }
}